// Round 1
// baseline (5111.380 us; speedup 1.0000x reference)
//
#include <hip/hip_runtime.h>

#define B_   2
#define S_   1024
#define D_   2048
#define H_   16
#define KV_  4
#define HD_  128
#define NTOK (B_ * S_)        /* 2048 tokens */
#define QD   (H_ * HD_)       /* 2048 */
#define KD   (KV_ * HD_)      /* 512  */

// ---------------------------------------------------------------------------
// mag = mean(sqrt(wr^2 + wi^2)) : partial sums via block reduce + atomicAdd.
// out must be zeroed before launch (hipMemsetAsync in kernel_launch).
// ---------------------------------------------------------------------------
__global__ __launch_bounds__(256)
void mag_reduce_kernel(const float* __restrict__ wr, const float* __restrict__ wi,
                       int n, float* __restrict__ out)
{
    __shared__ float red[256];
    float s = 0.f;
    for (int i = blockIdx.x * 256 + threadIdx.x; i < n; i += gridDim.x * 256) {
        float a = wr[i], b = wi[i];
        s += sqrtf(a * a + b * b);
    }
    red[threadIdx.x] = s;
    __syncthreads();
    for (int st = 128; st > 0; st >>= 1) {
        if (threadIdx.x < st) red[threadIdx.x] += red[threadIdx.x + st];
        __syncthreads();
    }
    if (threadIdx.x == 0) atomicAdd(out, red[0]);
}

// ---------------------------------------------------------------------------
// Per-token joint (re,im) absmax int8 quantization (STE fwd value).
// One block per token. Bitwise-matches the reference fp32 math:
// amax exact (max is order-independent), s = 127/max(amax,1e-5),
// rintf = round-half-to-even (jnp.round), clip, divide by s.
// ---------------------------------------------------------------------------
__global__ __launch_bounds__(256)
void act_quant_kernel(const float* __restrict__ xr, const float* __restrict__ xi,
                      float* __restrict__ qr, float* __restrict__ qi, int dim)
{
    const int tok = blockIdx.x;
    const float* pr = xr + (size_t)tok * dim;
    const float* pi = xi + (size_t)tok * dim;
    float am = 0.f;
    for (int d = threadIdx.x; d < dim; d += 256)
        am = fmaxf(am, fmaxf(fabsf(pr[d]), fabsf(pi[d])));
    __shared__ float red[256];
    red[threadIdx.x] = am;
    __syncthreads();
    for (int st = 128; st > 0; st >>= 1) {
        if (threadIdx.x < st) red[threadIdx.x] = fmaxf(red[threadIdx.x], red[threadIdx.x + st]);
        __syncthreads();
    }
    const float s = 127.0f / fmaxf(red[0], 1e-5f);
    float* oqr = qr + (size_t)tok * dim;
    float* oqi = qi + (size_t)tok * dim;
    for (int d = threadIdx.x; d < dim; d += 256) {
        float r_ = fminf(fmaxf(rintf(pr[d] * s), -128.f), 127.f);
        float i_ = fminf(fmaxf(rintf(pi[d] * s), -128.f), 127.f);
        oqr[d] = r_ / s;
        oqi[d] = i_ / s;
    }
}

// ---------------------------------------------------------------------------
// Complex GEMM with on-the-fly Fairy+-i weight quantization.
// x: [M x K] row-major (re,im), w: [K x N] row-major (re,im).
// qw = mag * (sr + i*si), sr/si in {-1,0,1}; mag factored out, applied at store.
// o_re = mag*(xr@sr - xi@si), o_im = mag*(xr@si + xi@sr).
// Tile 64x64, K-step 16, 256 threads, 4x4 micro-tile per thread.
// All dims are multiples of the tile sizes (M=2048, N in {512,2048}, K=2048).
// ---------------------------------------------------------------------------
#define GT_M 64
#define GT_N 64
#define GT_K 16

__global__ __launch_bounds__(256)
void cgemm_quant_kernel(const float* __restrict__ xr, const float* __restrict__ xi,
                        const float* __restrict__ wr, const float* __restrict__ wi,
                        const float* __restrict__ mag_sum, float inv_cnt,
                        int N, int K,
                        float* __restrict__ o_re, float* __restrict__ o_im)
{
    __shared__ float a_re[GT_K][GT_M];
    __shared__ float a_im[GT_K][GT_M];
    __shared__ float b_sr[GT_K][GT_N];
    __shared__ float b_si[GT_K][GT_N];

    const int tid = threadIdx.x;
    const int tx = tid & 15;      // n-lane
    const int ty = tid >> 4;      // m-lane
    const int bm = blockIdx.y * GT_M;
    const int bn = blockIdx.x * GT_N;
    const float mag = mag_sum[0] * inv_cnt;

    float acc_re[4][4] = {{0.f}}, acc_im[4][4] = {{0.f}};

    for (int k0 = 0; k0 < K; k0 += GT_K) {
        // stage A (activations)
#pragma unroll
        for (int r = 0; r < 4; ++r) {
            int idx = tid + 256 * r;
            int kk = idx & 15, m = idx >> 4;
            size_t g = (size_t)(bm + m) * K + (k0 + kk);
            a_re[kk][m] = xr[g];
            a_im[kk][m] = xi[g];
        }
        // stage B (weights, decoded to direction signs)
#pragma unroll
        for (int r = 0; r < 4; ++r) {
            int idx = tid + 256 * r;
            int n = idx & 63, kk = idx >> 6;
            size_t g = (size_t)(k0 + kk) * N + (bn + n);
            float wrv = wr[g], wiv = wi[g];
            float sr, si;
            if (fabsf(wrv) >= fabsf(wiv)) {
                sr = (wrv > 0.f) ? 1.f : ((wrv < 0.f) ? -1.f : 0.f);
                si = 0.f;
            } else {
                sr = 0.f;
                si = (wiv > 0.f) ? 1.f : ((wiv < 0.f) ? -1.f : 0.f);
            }
            b_sr[kk][n] = sr;
            b_si[kk][n] = si;
        }
        __syncthreads();
#pragma unroll
        for (int kk = 0; kk < GT_K; ++kk) {
            float ar[4], ai[4], br[4], bi[4];
#pragma unroll
            for (int i = 0; i < 4; ++i) { ar[i] = a_re[kk][ty + 16 * i]; ai[i] = a_im[kk][ty + 16 * i]; }
#pragma unroll
            for (int j = 0; j < 4; ++j) { br[j] = b_sr[kk][tx + 16 * j]; bi[j] = b_si[kk][tx + 16 * j]; }
#pragma unroll
            for (int i = 0; i < 4; ++i)
#pragma unroll
                for (int j = 0; j < 4; ++j) {
                    acc_re[i][j] = fmaf(ar[i], br[j], fmaf(-ai[i], bi[j], acc_re[i][j]));
                    acc_im[i][j] = fmaf(ar[i], bi[j], fmaf(ai[i], br[j], acc_im[i][j]));
                }
        }
        __syncthreads();
    }
#pragma unroll
    for (int i = 0; i < 4; ++i) {
        int m = bm + ty + 16 * i;
#pragma unroll
        for (int j = 0; j < 4; ++j) {
            int n = bn + tx + 16 * j;
            size_t g = (size_t)m * N + n;
            o_re[g] = mag * acc_re[i][j];
            o_im[g] = mag * acc_im[i][j];
        }
    }
}

// ---------------------------------------------------------------------------
// RoPE applied in place to the REAL component only. Layout [B,S,nh,128].
// pair (d, d+64) shares freq f = 10000^(-d/64):
//   x'[d]    = x[d]*cos - x[d+64]*sin
//   x'[d+64] = x[d+64]*cos + x[d]*sin
// ---------------------------------------------------------------------------
__global__ __launch_bounds__(256)
void rope_kernel(float* __restrict__ x, int nheads, int total)
{
    int idx = blockIdx.x * 256 + threadIdx.x;
    if (idx >= total) return;
    int d = idx & 63;
    int rest = idx >> 6;
    int hh = rest % nheads;
    int tok = rest / nheads;          // b*S + s
    int s = tok & (S_ - 1);
    float f = powf(10000.0f, -(float)d * (1.0f / 64.0f));
    float ang = (float)s * f;
    float sn, c;
    sincosf(ang, &sn, &c);
    size_t base = ((size_t)tok * nheads + hh) * HD_ + d;
    float x0 = x[base], x1 = x[base + 64];
    x[base]      = x0 * c - x1 * sn;
    x[base + 64] = x1 * c + x0 * sn;
}

// ---------------------------------------------------------------------------
// Causal flash attention (fp32, online softmax).
// scores = (q_re.k_re + q_im.k_im)/sqrt(128); o = softmax(scores) @ v (re,im).
// One block per (b, h, 16 q-rows); K/V tiles of 32 staged in LDS.
// q/o layout: [B,S,H,128] token-major; k/v layout: [B,S,KV,128].
// ---------------------------------------------------------------------------
#define AQ 16
#define AK 32
#define BIGNEG -3.0e38f

__global__ __launch_bounds__(256)
void attn_kernel(const float* __restrict__ q_re, const float* __restrict__ q_im,
                 const float* __restrict__ k_re, const float* __restrict__ k_im,
                 const float* __restrict__ v_re, const float* __restrict__ v_im,
                 float* __restrict__ o_re, float* __restrict__ o_im)
{
    __shared__ alignas(16) float sq_re[AQ][HD_ + 4];
    __shared__ alignas(16) float sq_im[AQ][HD_ + 4];
    __shared__ alignas(16) float sk_re[AK][HD_ + 4];
    __shared__ alignas(16) float sk_im[AK][HD_ + 4];
    __shared__ alignas(16) float sv_re[AK][HD_ + 4];
    __shared__ alignas(16) float sv_im[AK][HD_ + 4];
    __shared__ float sp[AQ][AK + 1];
    __shared__ float sm[AQ], sl[AQ], salpha[AQ];

    const int tid = threadIdx.x;
    const int qt = blockIdx.x, h = blockIdx.y, b = blockIdx.z;
    const int kvh = h / (H_ / KV_);
    const int q0 = qt * AQ;

    for (int idx = tid; idx < AQ * HD_; idx += 256) {
        int r = idx >> 7, d = idx & 127;
        size_t g = ((size_t)((b * S_ + q0 + r) * H_ + h)) * HD_ + d;
        sq_re[r][d] = q_re[g];
        sq_im[r][d] = q_im[g];
    }
    if (tid < AQ) { sm[tid] = BIGNEG; sl[tid] = 0.f; }

    const int my_r = tid >> 4;        // q-row owned in PV phase
    const int myg = tid & 15;         // dim group: 8 dims starting at myg*8
    float4 ar0 = {0, 0, 0, 0}, ar1 = {0, 0, 0, 0};
    float4 ai0 = {0, 0, 0, 0}, ai1 = {0, 0, 0, 0};

    __syncthreads();

    const int kmax = q0 + AQ;
    for (int c0 = 0; c0 < kmax; c0 += AK) {
        for (int idx = tid; idx < AK * HD_; idx += 256) {
            int r = idx >> 7, d = idx & 127;
            size_t g = ((size_t)((b * S_ + c0 + r) * KV_ + kvh)) * HD_ + d;
            sk_re[r][d] = k_re[g];
            sk_im[r][d] = k_im[g];
            sv_re[r][d] = v_re[g];
            sv_im[r][d] = v_im[g];
        }
        __syncthreads();
        // ---- scores: thread -> (r = tid&15, c = (tid>>4)*2 + si) ----
        {
            int r = tid & 15;
            const float4* qr4 = (const float4*)sq_re[r];
            const float4* qi4 = (const float4*)sq_im[r];
#pragma unroll
            for (int si = 0; si < 2; ++si) {
                int c = ((tid >> 4) << 1) + si;
                const float4* kr4 = (const float4*)sk_re[c];
                const float4* ki4 = (const float4*)sk_im[c];
                float acc = 0.f;
#pragma unroll 4
                for (int d4 = 0; d4 < HD_ / 4; ++d4) {
                    float4 a = qr4[d4], kk = kr4[d4];
                    float4 bb = qi4[d4], ll = ki4[d4];
                    acc += a.x * kk.x + a.y * kk.y + a.z * kk.z + a.w * kk.w
                         + bb.x * ll.x + bb.y * ll.y + bb.z * ll.z + bb.w * ll.w;
                }
                acc *= 0.08838834764831845f;   // 1/sqrt(128)
                if (c0 + c > q0 + r) acc = BIGNEG;
                sp[r][c] = acc;
            }
        }
        __syncthreads();
        // ---- online softmax state update (one thread per q-row) ----
        if (tid < AQ) {
            float mx = sm[tid];
#pragma unroll
            for (int c = 0; c < AK; ++c) mx = fmaxf(mx, sp[tid][c]);
            float alpha = __expf(sm[tid] - mx);
            float lsum = sl[tid] * alpha;
#pragma unroll
            for (int c = 0; c < AK; ++c) {
                float p = __expf(sp[tid][c] - mx);
                sp[tid][c] = p;
                lsum += p;
            }
            sm[tid] = mx; sl[tid] = lsum; salpha[tid] = alpha;
        }
        __syncthreads();
        // ---- PV accumulate ----
        {
            float alpha = salpha[my_r];
            ar0.x *= alpha; ar0.y *= alpha; ar0.z *= alpha; ar0.w *= alpha;
            ar1.x *= alpha; ar1.y *= alpha; ar1.z *= alpha; ar1.w *= alpha;
            ai0.x *= alpha; ai0.y *= alpha; ai0.z *= alpha; ai0.w *= alpha;
            ai1.x *= alpha; ai1.y *= alpha; ai1.z *= alpha; ai1.w *= alpha;
#pragma unroll 2
            for (int c = 0; c < AK; ++c) {
                float p = sp[my_r][c];
                const float4* vr4 = (const float4*)sv_re[c];
                const float4* vi4 = (const float4*)sv_im[c];
                float4 v0 = vr4[myg * 2], v1 = vr4[myg * 2 + 1];
                float4 w0 = vi4[myg * 2], w1 = vi4[myg * 2 + 1];
                ar0.x += p * v0.x; ar0.y += p * v0.y; ar0.z += p * v0.z; ar0.w += p * v0.w;
                ar1.x += p * v1.x; ar1.y += p * v1.y; ar1.z += p * v1.z; ar1.w += p * v1.w;
                ai0.x += p * w0.x; ai0.y += p * w0.y; ai0.z += p * w0.z; ai0.w += p * w0.w;
                ai1.x += p * w1.x; ai1.y += p * w1.y; ai1.z += p * w1.z; ai1.w += p * w1.w;
            }
        }
        __syncthreads();
    }
    const float invl = 1.f / sl[my_r];
    size_t g = ((size_t)((b * S_ + q0 + my_r) * H_ + h)) * HD_ + myg * 8;
    float4 s0, s1;
    s0.x = ar0.x * invl; s0.y = ar0.y * invl; s0.z = ar0.z * invl; s0.w = ar0.w * invl;
    s1.x = ar1.x * invl; s1.y = ar1.y * invl; s1.z = ar1.z * invl; s1.w = ar1.w * invl;
    *(float4*)&o_re[g] = s0;
    *(float4*)&o_re[g + 4] = s1;
    s0.x = ai0.x * invl; s0.y = ai0.y * invl; s0.z = ai0.z * invl; s0.w = ai0.w * invl;
    s1.x = ai1.x * invl; s1.y = ai1.y * invl; s1.z = ai1.z * invl; s1.w = ai1.w * invl;
    *(float4*)&o_im[g] = s0;
    *(float4*)&o_im[g + 4] = s1;
}

// ---------------------------------------------------------------------------
extern "C" void kernel_launch(void* const* d_in, const int* in_sizes, int n_in,
                              void* d_out, int out_size, void* d_ws, size_t ws_size,
                              hipStream_t stream)
{
    const float* hr    = (const float*)d_in[0];
    const float* hi    = (const float*)d_in[1];
    const float* wq_re = (const float*)d_in[2];
    const float* wq_im = (const float*)d_in[3];
    const float* wk_re = (const float*)d_in[4];
    const float* wk_im = (const float*)d_in[5];
    const float* wv_re = (const float*)d_in[6];
    const float* wv_im = (const float*)d_in[7];
    const float* wo_re = (const float*)d_in[8];
    const float* wo_im = (const float*)d_in[9];
    float* out = (float*)d_out;
    float* ws  = (float*)d_ws;

    // workspace layout (floats)
    float* mags  = ws;                       // [0..3] weight-mag sums (zeroed)
    float* qx_re = ws + 8;                   // NTOK*D   quantized hidden / later quantized o
    float* qx_im = qx_re + (size_t)NTOK * D_;
    float* q_re  = qx_im + (size_t)NTOK * D_;   // NTOK*QD
    float* q_im  = q_re + (size_t)NTOK * QD;
    float* k_re  = q_im + (size_t)NTOK * QD;    // NTOK*KD
    float* k_im  = k_re + (size_t)NTOK * KD;
    float* v_re  = k_im + (size_t)NTOK * KD;
    float* v_im  = v_re + (size_t)NTOK * KD;
    float* o_re  = v_im + (size_t)NTOK * KD;    // NTOK*QD
    float* o_im  = o_re + (size_t)NTOK * QD;

    size_t need = (size_t)(8 + 2 * NTOK * (size_t)D_ + 4 * NTOK * (size_t)QD
                           + 4 * NTOK * (size_t)KD) * sizeof(float);
    if (ws_size < need) return;   // insufficient scratch; fail loudly via validation

    hipMemsetAsync(d_ws, 0, 32, stream);

    mag_reduce_kernel<<<512, 256, 0, stream>>>(wq_re, wq_im, D_ * QD, mags + 0);
    mag_reduce_kernel<<<256, 256, 0, stream>>>(wk_re, wk_im, D_ * KD, mags + 1);
    mag_reduce_kernel<<<256, 256, 0, stream>>>(wv_re, wv_im, D_ * KD, mags + 2);
    mag_reduce_kernel<<<512, 256, 0, stream>>>(wo_re, wo_im, QD * D_, mags + 3);

    act_quant_kernel<<<NTOK, 256, 0, stream>>>(hr, hi, qx_re, qx_im, D_);

    dim3 gq(QD / GT_N, NTOK / GT_M);   // (32,32)
    dim3 gk(KD / GT_N, NTOK / GT_M);   // (8,32)
    cgemm_quant_kernel<<<gq, 256, 0, stream>>>(qx_re, qx_im, wq_re, wq_im, mags + 0,
                                               1.0f / (float)(D_ * QD), QD, D_, q_re, q_im);
    cgemm_quant_kernel<<<gk, 256, 0, stream>>>(qx_re, qx_im, wk_re, wk_im, mags + 1,
                                               1.0f / (float)(D_ * KD), KD, D_, k_re, k_im);
    cgemm_quant_kernel<<<gk, 256, 0, stream>>>(qx_re, qx_im, wv_re, wv_im, mags + 2,
                                               1.0f / (float)(D_ * KD), KD, D_, v_re, v_im);

    {
        int totq = NTOK * H_ * 64;
        rope_kernel<<<(totq + 255) / 256, 256, 0, stream>>>(q_re, H_, totq);
        int totk = NTOK * KV_ * 64;
        rope_kernel<<<(totk + 255) / 256, 256, 0, stream>>>(k_re, KV_, totk);
    }

    dim3 ga(S_ / AQ, H_, B_);          // (64,16,2)
    attn_kernel<<<ga, 256, 0, stream>>>(q_re, q_im, k_re, k_im, v_re, v_im, o_re, o_im);

    act_quant_kernel<<<NTOK, 256, 0, stream>>>(o_re, o_im, qx_re, qx_im, QD);

    cgemm_quant_kernel<<<gq, 256, 0, stream>>>(qx_re, qx_im, wo_re, wo_im, mags + 3,
                                               1.0f / (float)(QD * D_), D_, QD,
                                               out, out + (size_t)NTOK * D_);
}

// Round 2
// 1306.781 us; speedup vs baseline: 3.9114x; 3.9114x over previous
//
#include <hip/hip_runtime.h>
#include <stdint.h>

#define B_   2
#define S_   1024
#define D_   2048
#define H_   16
#define KV_  4
#define HD_  128
#define NTOK (B_ * S_)        /* 2048 tokens */
#define QD   (H_ * HD_)       /* 2048 */
#define KD   (KV_ * HD_)      /* 512  */

using i32x4  = __attribute__((ext_vector_type(4)))  int;
using i32x16 = __attribute__((ext_vector_type(16))) int;

// ---------------- bf16 pack/unpack helpers (re in low 16, im in high 16) ----
__device__ __forceinline__ float bflo(uint32_t u) { return __uint_as_float(u << 16); }
__device__ __forceinline__ float bfhi(uint32_t u) { return __uint_as_float(u & 0xFFFF0000u); }
__device__ __forceinline__ uint16_t f2bf(float f) {
    uint32_t u = __float_as_uint(f);
    uint32_t r = (u + 0x7FFFu + ((u >> 16) & 1u)) >> 16;   // RNE
    return (uint16_t)r;
}
__device__ __forceinline__ uint32_t pack_bf(float re, float im) {
    return (uint32_t)f2bf(re) | ((uint32_t)f2bf(im) << 16);
}

// ---------------------------------------------------------------------------
// mag = mean(sqrt(wr^2+wi^2)): block reduce + atomicAdd into zeroed slot.
// ---------------------------------------------------------------------------
__global__ __launch_bounds__(256)
void mag_reduce_kernel(const float* __restrict__ wr, const float* __restrict__ wi,
                       int n, float* __restrict__ out)
{
    __shared__ float red[256];
    float s = 0.f;
    for (int i = blockIdx.x * 256 + threadIdx.x; i < n; i += gridDim.x * 256) {
        float a = wr[i], b = wi[i];
        s += sqrtf(a * a + b * b);
    }
    red[threadIdx.x] = s;
    __syncthreads();
    for (int st = 128; st > 0; st >>= 1) {
        if (threadIdx.x < st) red[threadIdx.x] += red[threadIdx.x + st];
        __syncthreads();
    }
    if (threadIdx.x == 0) atomicAdd(out, red[0]);
}

// ---------------------------------------------------------------------------
// Per-token joint absmax int8 quantization. dim = 2048 exactly:
// 256 threads x 8 elements per plane. Outputs int8 planes + invs[tok] = 1/s.
// Matches reference: s = 127/max(amax,1e-5); rintf = RNE = jnp.round.
// ---------------------------------------------------------------------------
__global__ __launch_bounds__(256)
void act_quant_i8_kernel(const float* __restrict__ xr, const float* __restrict__ xi,
                         int8_t* __restrict__ qr, int8_t* __restrict__ qi,
                         float* __restrict__ invs)
{
    const int tok = blockIdx.x, t = threadIdx.x;
    const float* pr = xr + (size_t)tok * 2048 + t * 8;
    const float* pi = xi + (size_t)tok * 2048 + t * 8;
    float4 r0 = *(const float4*)pr, r1 = *(const float4*)(pr + 4);
    float4 i0 = *(const float4*)pi, i1 = *(const float4*)(pi + 4);
    float am = fmaxf(fmaxf(fmaxf(fabsf(r0.x), fabsf(r0.y)), fmaxf(fabsf(r0.z), fabsf(r0.w))),
                     fmaxf(fmaxf(fabsf(r1.x), fabsf(r1.y)), fmaxf(fabsf(r1.z), fabsf(r1.w))));
    am = fmaxf(am, fmaxf(fmaxf(fmaxf(fabsf(i0.x), fabsf(i0.y)), fmaxf(fabsf(i0.z), fabsf(i0.w))),
                         fmaxf(fmaxf(fabsf(i1.x), fabsf(i1.y)), fmaxf(fabsf(i1.z), fabsf(i1.w)))));
    __shared__ float red[256];
    red[t] = am;
    __syncthreads();
    for (int st = 128; st > 0; st >>= 1) {
        if (t < st) red[t] = fmaxf(red[t], red[t + st]);
        __syncthreads();
    }
    const float s = 127.0f / fmaxf(red[0], 1e-5f);
    if (t == 0) invs[tok] = 1.0f / s;
#define Q8(x) ((uint32_t)(uint8_t)(int8_t)(int)fminf(fmaxf(rintf((x) * s), -128.f), 127.f))
    uint32_t a0 = Q8(r0.x) | (Q8(r0.y) << 8) | (Q8(r0.z) << 16) | (Q8(r0.w) << 24);
    uint32_t a1 = Q8(r1.x) | (Q8(r1.y) << 8) | (Q8(r1.z) << 16) | (Q8(r1.w) << 24);
    uint32_t b0 = Q8(i0.x) | (Q8(i0.y) << 8) | (Q8(i0.z) << 16) | (Q8(i0.w) << 24);
    uint32_t b1 = Q8(i1.x) | (Q8(i1.y) << 8) | (Q8(i1.z) << 16) | (Q8(i1.w) << 24);
#undef Q8
    *(uint32_t*)(qr + (size_t)tok * 2048 + t * 8)     = a0;
    *(uint32_t*)(qr + (size_t)tok * 2048 + t * 8 + 4) = a1;
    *(uint32_t*)(qi + (size_t)tok * 2048 + t * 8)     = b0;
    *(uint32_t*)(qi + (size_t)tok * 2048 + t * 8 + 4) = b1;
}

// ---------------------------------------------------------------------------
// Weight decode + transpose: w [K x N] fp32 (re,im) -> sign planes [n][k] int8
// (sr, si, -si), written at row offset n_off, row stride 2048 (=K).
// 64x64 tile via LDS.
// ---------------------------------------------------------------------------
__global__ __launch_bounds__(256)
void decode_kernel(const float* __restrict__ wr, const float* __restrict__ wi,
                   int N, int8_t* __restrict__ psr, int8_t* __restrict__ psi,
                   int8_t* __restrict__ pnsi, int n_off)
{
    __shared__ alignas(16) int8_t tr[3][64][80];
    const int n0 = blockIdx.x * 64, k0 = blockIdx.y * 64;
    for (int idx = threadIdx.x; idx < 4096; idx += 256) {
        int j = idx & 63, i = idx >> 6;                 // j = n, i = k
        size_t g = (size_t)(k0 + i) * N + n0 + j;
        float a = wr[g], b = wi[g];
        int8_t sr, si;
        if (fabsf(a) >= fabsf(b)) {
            sr = (a > 0.f) ? 1 : ((a < 0.f) ? -1 : 0);
            si = 0;
        } else {
            sr = 0;
            si = (b > 0.f) ? 1 : ((b < 0.f) ? -1 : 0);
        }
        tr[0][j][i] = sr;
        tr[1][j][i] = si;
        tr[2][j][i] = (int8_t)(-si);
    }
    __syncthreads();
    int8_t* planes[3] = { psr, psi, pnsi };
    for (int idx = threadIdx.x; idx < 768; idx += 256) {
        int p = idx >> 8, rem = idx & 255, n = rem >> 2, c = rem & 3;
        int4 v = *(const int4*)&tr[p][n][c * 16];
        *(int4*)(planes[p] + (size_t)(n_off + n0 + n) * 2048 + k0 + c * 16) = v;
    }
}

// ---------------------------------------------------------------------------
// int8 MFMA complex GEMM. A planes: xr,xi int8 [M x K] (K=2048). B planes:
// sr,si,nsi int8 [N x K] (transposed signs). 128x128 tile, BK=64, 4 waves,
// each wave 2x2 blocks of mfma_i32_32x32x32_i8.
//   acc_re = xr@sr + xi@(-si);  acc_im = xr@si + xi@sr   (exact i32)
// Epilogue: scale = mag * invs[row].
//   MODE 0 (QKV): col<2048 -> q fp32 planes; <2560 -> k packed bf16; else v.
//   MODE 1 (out): plain fp32 planes, stride Nout.
// LDS layout per plane: [chunk c(0..3)][row(0..127)][16B], conflict-free b128.
// ---------------------------------------------------------------------------
__device__ __forceinline__ void async_copy16(const void* g, void* l) {
    __builtin_amdgcn_global_load_lds((const __attribute__((address_space(1))) void*)g,
                                     (__attribute__((address_space(3))) void*)l, 16, 0, 0);
}

template <int MODE>
__global__ __launch_bounds__(256)
void gemm_i8_kernel(const int8_t* __restrict__ axr, const int8_t* __restrict__ axi,
                    const int8_t* __restrict__ bsr, const int8_t* __restrict__ bsi,
                    const int8_t* __restrict__ bnsi,
                    int Nout, const float* __restrict__ invs,
                    const float* __restrict__ mag_sums,
                    float magc0, float magc1, float magc2,
                    float* o_re, float* o_im, uint32_t* k_pk, uint32_t* v_pk)
{
    __shared__ alignas(16) int8_t smem[5 * 8192];
    const int tid = threadIdx.x;
    const int wav = tid >> 6, lane = tid & 63;
    const int tileM = blockIdx.y * 128, tileN = blockIdx.x * 128;
    const int wm = wav & 1, wn = wav >> 1;
    const int K = 2048;

    const int8_t* gplane[5] = { axr, axi, bsr, bsi, bnsi };
    const int     rbase[5]  = { tileM, tileM, tileN, tileN, tileN };

    i32x16 acc_re[2][2] = {};
    i32x16 acc_im[2][2] = {};

    for (int k0 = 0; k0 < K; k0 += 64) {
#pragma unroll
        for (int i = 0; i < 10; ++i) {
            int q = wav + 4 * i;            // 40 instructions, 10 per wave
            int pl = q >> 3, seg = q & 7;
            int c = seg >> 1, m0 = (seg & 1) << 6;
            const int8_t* g = gplane[pl] + (size_t)(rbase[pl] + m0 + lane) * K + k0 + c * 16;
            int8_t* l = &smem[pl * 8192 + (c * 128 + m0) * 16];
            async_copy16(g, l);
        }
        __syncthreads();
#pragma unroll
        for (int s = 0; s < 2; ++s) {
            const int cc = 2 * s + (lane >> 5);
            const int rA = wm * 64 + (lane & 31);
            const int rB = wn * 64 + (lane & 31);
            i32x4 fxr[2], fxi[2], fsr[2], fsi[2], fns[2];
#pragma unroll
            for (int mb = 0; mb < 2; ++mb) {
                int off = (cc * 128 + rA + mb * 32) * 16;
                fxr[mb] = *(const i32x4*)&smem[0 * 8192 + off];
                fxi[mb] = *(const i32x4*)&smem[1 * 8192 + off];
            }
#pragma unroll
            for (int nb = 0; nb < 2; ++nb) {
                int off = (cc * 128 + rB + nb * 32) * 16;
                fsr[nb] = *(const i32x4*)&smem[2 * 8192 + off];
                fsi[nb] = *(const i32x4*)&smem[3 * 8192 + off];
                fns[nb] = *(const i32x4*)&smem[4 * 8192 + off];
            }
#pragma unroll
            for (int mb = 0; mb < 2; ++mb)
#pragma unroll
                for (int nb = 0; nb < 2; ++nb) {
                    acc_re[mb][nb] = __builtin_amdgcn_mfma_i32_32x32x32_i8(fxr[mb], fsr[nb], acc_re[mb][nb], 0, 0, 0);
                    acc_re[mb][nb] = __builtin_amdgcn_mfma_i32_32x32x32_i8(fxi[mb], fns[nb], acc_re[mb][nb], 0, 0, 0);
                    acc_im[mb][nb] = __builtin_amdgcn_mfma_i32_32x32x32_i8(fxr[mb], fsi[nb], acc_im[mb][nb], 0, 0, 0);
                    acc_im[mb][nb] = __builtin_amdgcn_mfma_i32_32x32x32_i8(fxi[mb], fsr[nb], acc_im[mb][nb], 0, 0, 0);
                }
        }
        __syncthreads();
    }

    const int ln31 = lane & 31, lq = lane >> 5;
#pragma unroll
    for (int mb = 0; mb < 2; ++mb) {
#pragma unroll
        for (int nb = 0; nb < 2; ++nb) {
            const int gn = tileN + wn * 64 + nb * 32 + ln31;
            float mag;
            if (MODE == 0)
                mag = (gn < 2048) ? mag_sums[0] * magc0
                    : (gn < 2560) ? mag_sums[1] * magc1
                                  : mag_sums[2] * magc2;
            else
                mag = mag_sums[0] * magc0;
#pragma unroll
            for (int r = 0; r < 16; ++r) {
                const int row = (r & 3) + 8 * (r >> 2) + 4 * lq;
                const int gm = tileM + wm * 64 + mb * 32 + row;
                const float sc = mag * invs[gm];
                const float re = (float)acc_re[mb][nb][r] * sc;
                const float im = (float)acc_im[mb][nb][r] * sc;
                if (MODE == 1) {
                    o_re[(size_t)gm * Nout + gn] = re;
                    o_im[(size_t)gm * Nout + gn] = im;
                } else {
                    if (gn < 2048) {
                        o_re[(size_t)gm * 2048 + gn] = re;
                        o_im[(size_t)gm * 2048 + gn] = im;
                    } else if (gn < 2560) {
                        k_pk[(size_t)gm * 512 + (gn - 2048)] = pack_bf(re, im);
                    } else {
                        v_pk[(size_t)gm * 512 + (gn - 2560)] = pack_bf(re, im);
                    }
                }
            }
        }
    }
}

// ---------------------------------------------------------------------------
// RoPE in place, fp32 real plane of q. Layout [tok][nh][128].
// ---------------------------------------------------------------------------
__global__ __launch_bounds__(256)
void rope_kernel(float* __restrict__ x, int nheads, int total)
{
    int idx = blockIdx.x * 256 + threadIdx.x;
    if (idx >= total) return;
    int d = idx & 63;
    int rest = idx >> 6;
    int hh = rest % nheads;
    int tok = rest / nheads;
    int s = tok & (S_ - 1);
    float f = __expf(-(float)d * (0.14392519f));   // ln(10000)/64 = 0.143925...
    float ang = (float)s * f;
    float sn, c;
    __sincosf(ang, &sn, &c);
    size_t base = ((size_t)tok * nheads + hh) * HD_ + d;
    float x0 = x[base], x1 = x[base + 64];
    x[base]      = x0 * c - x1 * sn;
    x[base + 64] = x1 * c + x0 * sn;
}

// RoPE in place on packed bf16 k (rotates re = low16, keeps im = high16).
__global__ __launch_bounds__(256)
void rope_pk_kernel(uint32_t* __restrict__ kp, int total)
{
    int idx = blockIdx.x * 256 + threadIdx.x;
    if (idx >= total) return;
    int d = idx & 63;
    int rest = idx >> 6;
    int kvh = rest & (KV_ - 1);
    int tok = rest / KV_;
    int s = tok & (S_ - 1);
    float f = __expf(-(float)d * (0.14392519f));
    float ang = (float)s * f;
    float sn, c;
    __sincosf(ang, &sn, &c);
    size_t base = ((size_t)tok * KV_ + kvh) * HD_ + d;
    uint32_t u0 = kp[base], u1 = kp[base + 64];
    float r0 = bflo(u0), r1 = bflo(u1);
    float n0 = r0 * c - r1 * sn;
    float n1 = r1 * c + r0 * sn;
    kp[base]      = (u0 & 0xFFFF0000u) | f2bf(n0);
    kp[base + 64] = (u1 & 0xFFFF0000u) | f2bf(n1);
}

// ---------------------------------------------------------------------------
// Causal flash attention, online softmax. q fp32 [tok][16][128]; k/v packed
// bf16 (re|im) [tok][4][128]. 16 q-rows per block, K-tiles of 32.
// LDS ~53KB -> 3 blocks/CU. Softmax fully parallel via 16-lane shuffles.
// o may alias q (block reads exactly the rows/head it writes, staged first).
// ---------------------------------------------------------------------------
#define AQ 16
#define AK 32

__global__ __launch_bounds__(256)
void attn_kernel(const float* q_re, const float* q_im,
                 const uint32_t* __restrict__ k_pk, const uint32_t* __restrict__ v_pk,
                 float* o_re, float* o_im)
{
    __shared__ alignas(16) float    sq_re[AQ][132];
    __shared__ alignas(16) float    sq_im[AQ][132];
    __shared__ alignas(16) uint32_t sk[AK][132];
    __shared__ alignas(16) uint32_t sv[AK][132];
    __shared__ float sp[AQ][AK + 1];
    __shared__ float sm_[AQ], sl_[AQ], sal_[AQ];

    const int tid = threadIdx.x;
    const int qt = blockIdx.x, h = blockIdx.y, b = blockIdx.z;
    const int kvh = h >> 2;
    const int q0 = qt * AQ;

    for (int idx = tid; idx < 1024; idx += 256) {
        int p = idx >> 9, rem = idx & 511, r = rem >> 5, d4 = rem & 31;
        const float* src = p ? q_im : q_re;
        float4 v = *(const float4*)&src[(((size_t)(b * S_ + q0 + r) * H_ + h) << 7) + d4 * 4];
        float* dst = p ? &sq_im[r][d4 * 4] : &sq_re[r][d4 * 4];
        *(float4*)dst = v;
    }
    if (tid < AQ) { sm_[tid] = -3e38f; sl_[tid] = 0.f; }
    __syncthreads();

    const int my_r = tid >> 4, myg = tid & 15;
    const int d0 = myg * 4, d1 = 64 + myg * 4;
    float4 ar0 = {0,0,0,0}, ar1 = {0,0,0,0}, ai0 = {0,0,0,0}, ai1 = {0,0,0,0};

    const int kmax = q0 + AQ;
    for (int c0 = 0; c0 < kmax; c0 += AK) {
        // stage K,V tiles (packed)
        for (int idx = tid; idx < 2048; idx += 256) {
            int a = idx >> 10, rem = idx & 1023, r = rem >> 5, d4 = rem & 31;
            const uint32_t* src = a ? v_pk : k_pk;
            uint4 v = *(const uint4*)&src[(((size_t)(b * S_ + c0 + r) * KV_ + kvh) << 7) + d4 * 4];
            uint32_t* dst = a ? &sv[r][d4 * 4] : &sk[r][d4 * 4];
            *(uint4*)dst = v;
        }
        __syncthreads();
        // ---- scores ----
        {
            const int r = tid & 15;
            const int cb = (tid >> 4) << 1;
            const float* qr = sq_re[r];
            const float* qi = sq_im[r];
#pragma unroll
            for (int si = 0; si < 2; ++si) {
                const int c = cb + si;
                const uint32_t* krow = sk[c];
                float acc = 0.f;
#pragma unroll 8
                for (int d4 = 0; d4 < 32; ++d4) {
                    uint4  kk  = *(const uint4*)&krow[d4 * 4];
                    float4 qrv = *(const float4*)&qr[d4 * 4];
                    float4 qiv = *(const float4*)&qi[d4 * 4];
                    acc = fmaf(qrv.x, bflo(kk.x), acc);
                    acc = fmaf(qiv.x, bfhi(kk.x), acc);
                    acc = fmaf(qrv.y, bflo(kk.y), acc);
                    acc = fmaf(qiv.y, bfhi(kk.y), acc);
                    acc = fmaf(qrv.z, bflo(kk.z), acc);
                    acc = fmaf(qiv.z, bfhi(kk.z), acc);
                    acc = fmaf(qrv.w, bflo(kk.w), acc);
                    acc = fmaf(qiv.w, bfhi(kk.w), acc);
                }
                acc *= 0.08838834764831845f;
                if (c0 + c > q0 + r) acc = -3e38f;
                sp[r][c] = acc;
            }
        }
        __syncthreads();
        // ---- softmax: 16 threads per row, same-wave shuffle reduce ----
        {
            const int r = tid >> 4, j = tid & 15;
            float p0 = sp[r][2 * j], p1 = sp[r][2 * j + 1];
            float mx = fmaxf(p0, p1);
#pragma unroll
            for (int m = 1; m < 16; m <<= 1) mx = fmaxf(mx, __shfl_xor(mx, m));
            mx = fmaxf(mx, sm_[r]);
            float e0 = __expf(p0 - mx), e1 = __expf(p1 - mx);
            sp[r][2 * j] = e0; sp[r][2 * j + 1] = e1;
            float lsum = e0 + e1;
#pragma unroll
            for (int m = 1; m < 16; m <<= 1) lsum += __shfl_xor(lsum, m);
            if (j == 0) {
                float alpha = __expf(sm_[r] - mx);
                sal_[r] = alpha;
                sl_[r]  = sl_[r] * alpha + lsum;
                sm_[r]  = mx;
            }
        }
        __syncthreads();
        // ---- PV ----
        {
            const float alpha = sal_[my_r];
            ar0.x *= alpha; ar0.y *= alpha; ar0.z *= alpha; ar0.w *= alpha;
            ar1.x *= alpha; ar1.y *= alpha; ar1.z *= alpha; ar1.w *= alpha;
            ai0.x *= alpha; ai0.y *= alpha; ai0.z *= alpha; ai0.w *= alpha;
            ai1.x *= alpha; ai1.y *= alpha; ai1.z *= alpha; ai1.w *= alpha;
#pragma unroll 4
            for (int c = 0; c < AK; ++c) {
                const float p = sp[my_r][c];
                uint4 v0 = *(const uint4*)&sv[c][d0];
                uint4 v1 = *(const uint4*)&sv[c][d1];
                ar0.x = fmaf(p, bflo(v0.x), ar0.x); ai0.x = fmaf(p, bfhi(v0.x), ai0.x);
                ar0.y = fmaf(p, bflo(v0.y), ar0.y); ai0.y = fmaf(p, bfhi(v0.y), ai0.y);
                ar0.z = fmaf(p, bflo(v0.z), ar0.z); ai0.z = fmaf(p, bfhi(v0.z), ai0.z);
                ar0.w = fmaf(p, bflo(v0.w), ar0.w); ai0.w = fmaf(p, bfhi(v0.w), ai0.w);
                ar1.x = fmaf(p, bflo(v1.x), ar1.x); ai1.x = fmaf(p, bfhi(v1.x), ai1.x);
                ar1.y = fmaf(p, bflo(v1.y), ar1.y); ai1.y = fmaf(p, bfhi(v1.y), ai1.y);
                ar1.z = fmaf(p, bflo(v1.z), ar1.z); ai1.z = fmaf(p, bfhi(v1.z), ai1.z);
                ar1.w = fmaf(p, bflo(v1.w), ar1.w); ai1.w = fmaf(p, bfhi(v1.w), ai1.w);
            }
        }
        __syncthreads();
    }
    const float invl = 1.f / sl_[my_r];
    const size_t gbase = (((size_t)(b * S_ + q0 + my_r) * H_ + h) << 7);
    float4 s0;
    s0.x = ar0.x * invl; s0.y = ar0.y * invl; s0.z = ar0.z * invl; s0.w = ar0.w * invl;
    *(float4*)&o_re[gbase + d0] = s0;
    s0.x = ar1.x * invl; s0.y = ar1.y * invl; s0.z = ar1.z * invl; s0.w = ar1.w * invl;
    *(float4*)&o_re[gbase + d1] = s0;
    s0.x = ai0.x * invl; s0.y = ai0.y * invl; s0.z = ai0.z * invl; s0.w = ai0.w * invl;
    *(float4*)&o_im[gbase + d0] = s0;
    s0.x = ai1.x * invl; s0.y = ai1.y * invl; s0.z = ai1.z * invl; s0.w = ai1.w * invl;
    *(float4*)&o_im[gbase + d1] = s0;
}

// ---------------------------------------------------------------------------
extern "C" void kernel_launch(void* const* d_in, const int* in_sizes, int n_in,
                              void* d_out, int out_size, void* d_ws, size_t ws_size,
                              hipStream_t stream)
{
    const float* hr    = (const float*)d_in[0];
    const float* hi    = (const float*)d_in[1];
    const float* wq_re = (const float*)d_in[2];
    const float* wq_im = (const float*)d_in[3];
    const float* wk_re = (const float*)d_in[4];
    const float* wk_im = (const float*)d_in[5];
    const float* wv_re = (const float*)d_in[6];
    const float* wv_im = (const float*)d_in[7];
    const float* wo_re = (const float*)d_in[8];
    const float* wo_im = (const float*)d_in[9];
    float* out = (float*)d_out;
    char*  base = (char*)d_ws;

    // ---- workspace layout (all 16B-aligned) ----
    const size_t MB4  = (size_t)2048 * 2048;        // 4 MB int8 plane
    const size_t QKVP = (size_t)3072 * 2048;        // 6.29 MB int8 plane
    float*   mags   = (float*)(base + 0);           // 4 floats, zeroed
    float*   invs1  = (float*)(base + 1024);
    float*   invs2  = (float*)(base + 1024 + 8192);
    int8_t*  xr_q   = (int8_t*)(base + 32768);
    int8_t*  xi_q   = xr_q + MB4;
    int8_t*  qkv_sr = xi_q + MB4;
    int8_t*  qkv_si = qkv_sr + QKVP;
    int8_t*  qkv_ns = qkv_si + QKVP;
    int8_t*  wo_sr  = qkv_ns + QKVP;
    int8_t*  wo_si  = wo_sr + MB4;
    int8_t*  wo_ns  = wo_si + MB4;
    float*   q_re   = (float*)(wo_ns + MB4);        // [tok][16][128]; reused as o_re
    float*   q_im   = q_re + MB4;
    uint32_t* k_pk  = (uint32_t*)(q_im + MB4);      // [tok][4][128] packed bf16
    uint32_t* v_pk  = k_pk + (size_t)2048 * 512;

    hipMemsetAsync(mags, 0, 16, stream);

    mag_reduce_kernel<<<512, 256, 0, stream>>>(wq_re, wq_im, D_ * QD, mags + 0);
    mag_reduce_kernel<<<256, 256, 0, stream>>>(wk_re, wk_im, D_ * KD, mags + 1);
    mag_reduce_kernel<<<256, 256, 0, stream>>>(wv_re, wv_im, D_ * KD, mags + 2);
    mag_reduce_kernel<<<512, 256, 0, stream>>>(wo_re, wo_im, QD * D_, mags + 3);

    // decode weights into transposed sign planes
    decode_kernel<<<dim3(32, 32), 256, 0, stream>>>(wq_re, wq_im, 2048, qkv_sr, qkv_si, qkv_ns, 0);
    decode_kernel<<<dim3(8, 32),  256, 0, stream>>>(wk_re, wk_im, 512,  qkv_sr, qkv_si, qkv_ns, 2048);
    decode_kernel<<<dim3(8, 32),  256, 0, stream>>>(wv_re, wv_im, 512,  qkv_sr, qkv_si, qkv_ns, 2560);
    decode_kernel<<<dim3(32, 32), 256, 0, stream>>>(wo_re, wo_im, 2048, wo_sr, wo_si, wo_ns, 0);

    act_quant_i8_kernel<<<NTOK, 256, 0, stream>>>(hr, hi, xr_q, xi_q, invs1);

    // fused QKV GEMM: N = 3072 (2048 q | 512 k | 512 v)
    gemm_i8_kernel<0><<<dim3(24, 16), 256, 0, stream>>>(
        xr_q, xi_q, qkv_sr, qkv_si, qkv_ns, 0, invs1, mags,
        1.0f / (float)((size_t)D_ * QD), 1.0f / (float)((size_t)D_ * KD), 1.0f / (float)((size_t)D_ * KD),
        q_re, q_im, k_pk, v_pk);

    rope_kernel<<<(NTOK * H_ * 64 + 255) / 256, 256, 0, stream>>>(q_re, H_, NTOK * H_ * 64);
    rope_pk_kernel<<<(NTOK * KV_ * 64 + 255) / 256, 256, 0, stream>>>(k_pk, NTOK * KV_ * 64);

    attn_kernel<<<dim3(S_ / AQ, H_, B_), 256, 0, stream>>>(q_re, q_im, k_pk, v_pk, q_re, q_im);

    act_quant_i8_kernel<<<NTOK, 256, 0, stream>>>(q_re, q_im, xr_q, xi_q, invs2);

    gemm_i8_kernel<1><<<dim3(16, 16), 256, 0, stream>>>(
        xr_q, xi_q, wo_sr, wo_si, wo_ns, 2048, invs2, mags + 3,
        1.0f / (float)((size_t)QD * D_), 0.f, 0.f,
        out, out + MB4, nullptr, nullptr);
}

// Round 4
// 598.751 us; speedup vs baseline: 8.5367x; 2.1825x over previous
//
#include <hip/hip_runtime.h>
#include <stdint.h>

#define B_   2
#define S_   1024
#define D_   2048
#define H_   16
#define KV_  4
#define HD_  128
#define NTOK (B_ * S_)        /* 2048 tokens */
#define QD   (H_ * HD_)       /* 2048 */
#define KD   (KV_ * HD_)      /* 512  */

using i32x4  = __attribute__((ext_vector_type(4)))  int;
using i32x16 = __attribute__((ext_vector_type(16))) int;
using f32x4  = __attribute__((ext_vector_type(4)))  float;
using bf16x8 = __attribute__((ext_vector_type(8)))  short;

#define LN1E4_OVER_64 0.14391156831212725f   /* ln(10000)/64 — round-2 constant was wrong */

// ---------------- bf16 helpers ---------------------------------------------
__device__ __forceinline__ float bf2f(uint16_t u) { return __uint_as_float((uint32_t)u << 16); }
__device__ __forceinline__ uint16_t f2bf(float f) {
    uint32_t u = __float_as_uint(f);
    return (uint16_t)((u + 0x7FFFu + ((u >> 16) & 1u)) >> 16);   // RNE
}

// ---------------------------------------------------------------------------
// Per-token joint absmax int8 quantization (dim = 2048 fixed).
// Matches reference: s = 127/max(amax,1e-5); rintf = RNE = jnp.round.
// ---------------------------------------------------------------------------
__global__ __launch_bounds__(256)
void act_quant_i8_kernel(const float* __restrict__ xr, const float* __restrict__ xi,
                         int8_t* __restrict__ qr, int8_t* __restrict__ qi,
                         float* __restrict__ invs)
{
    const int tok = blockIdx.x, t = threadIdx.x;
    const float* pr = xr + (size_t)tok * 2048 + t * 8;
    const float* pi = xi + (size_t)tok * 2048 + t * 8;
    float4 r0 = *(const float4*)pr, r1 = *(const float4*)(pr + 4);
    float4 i0 = *(const float4*)pi, i1 = *(const float4*)(pi + 4);
    float am = fmaxf(fmaxf(fmaxf(fabsf(r0.x), fabsf(r0.y)), fmaxf(fabsf(r0.z), fabsf(r0.w))),
                     fmaxf(fmaxf(fabsf(r1.x), fabsf(r1.y)), fmaxf(fabsf(r1.z), fabsf(r1.w))));
    am = fmaxf(am, fmaxf(fmaxf(fmaxf(fabsf(i0.x), fabsf(i0.y)), fmaxf(fabsf(i0.z), fabsf(i0.w))),
                         fmaxf(fmaxf(fabsf(i1.x), fabsf(i1.y)), fmaxf(fabsf(i1.z), fabsf(i1.w)))));
    __shared__ float red[256];
    red[t] = am;
    __syncthreads();
    for (int st = 128; st > 0; st >>= 1) {
        if (t < st) red[t] = fmaxf(red[t], red[t + st]);
        __syncthreads();
    }
    const float s = 127.0f / fmaxf(red[0], 1e-5f);
    if (t == 0) invs[tok] = 1.0f / s;
#define Q8(x) ((uint32_t)(uint8_t)(int8_t)(int)fminf(fmaxf(rintf((x) * s), -128.f), 127.f))
    uint32_t a0 = Q8(r0.x) | (Q8(r0.y) << 8) | (Q8(r0.z) << 16) | (Q8(r0.w) << 24);
    uint32_t a1 = Q8(r1.x) | (Q8(r1.y) << 8) | (Q8(r1.z) << 16) | (Q8(r1.w) << 24);
    uint32_t b0 = Q8(i0.x) | (Q8(i0.y) << 8) | (Q8(i0.z) << 16) | (Q8(i0.w) << 24);
    uint32_t b1 = Q8(i1.x) | (Q8(i1.y) << 8) | (Q8(i1.z) << 16) | (Q8(i1.w) << 24);
#undef Q8
    *(uint32_t*)(qr + (size_t)tok * 2048 + t * 8)     = a0;
    *(uint32_t*)(qr + (size_t)tok * 2048 + t * 8 + 4) = a1;
    *(uint32_t*)(qi + (size_t)tok * 2048 + t * 8)     = b0;
    *(uint32_t*)(qi + (size_t)tok * 2048 + t * 8 + 4) = b1;
}

// ---------------------------------------------------------------------------
// Weight decode + transpose + FUSED mag reduction.
// w [K x N] fp32 (re,im) -> sign planes [n][k] int8 (sr, si, -si) at row
// offset n_off (row stride 2048 = K), plus atomicAdd of sum |w| into mag_out.
// ---------------------------------------------------------------------------
__global__ __launch_bounds__(256)
void decode_kernel(const float* __restrict__ wr, const float* __restrict__ wi,
                   int N, int8_t* __restrict__ psr, int8_t* __restrict__ psi,
                   int8_t* __restrict__ pnsi, int n_off, float* __restrict__ mag_out)
{
    __shared__ alignas(16) int8_t tr[3][64][80];
    __shared__ float red[256];
    const int n0 = blockIdx.x * 64, k0 = blockIdx.y * 64;
    float msum = 0.f;
    for (int idx = threadIdx.x; idx < 4096; idx += 256) {
        int j = idx & 63, i = idx >> 6;                 // j = n, i = k
        size_t g = (size_t)(k0 + i) * N + n0 + j;
        float a = wr[g], b = wi[g];
        msum += sqrtf(a * a + b * b);
        int8_t sr, si;
        if (fabsf(a) >= fabsf(b)) {
            sr = (a > 0.f) ? 1 : ((a < 0.f) ? -1 : 0);
            si = 0;
        } else {
            sr = 0;
            si = (b > 0.f) ? 1 : ((b < 0.f) ? -1 : 0);
        }
        tr[0][j][i] = sr;
        tr[1][j][i] = si;
        tr[2][j][i] = (int8_t)(-si);
    }
    red[threadIdx.x] = msum;
    __syncthreads();
    for (int st = 128; st > 0; st >>= 1) {
        if (threadIdx.x < st) red[threadIdx.x] += red[threadIdx.x + st];
        __syncthreads();
    }
    if (threadIdx.x == 0) atomicAdd(mag_out, red[0]);
    int8_t* planes[3] = { psr, psi, pnsi };
    for (int idx = threadIdx.x; idx < 768; idx += 256) {
        int p = idx >> 8, rem = idx & 255, n = rem >> 2, c = rem & 3;
        int4 v = *(const int4*)&tr[p][n][c * 16];
        *(int4*)(planes[p] + (size_t)(n_off + n0 + n) * 2048 + k0 + c * 16) = v;
    }
}

// ---------------------------------------------------------------------------
// int8 MFMA complex GEMM (128x128 tile, BK=64, 4 waves, 2x2 32x32x32 blocks).
//   acc_re = xr@sr + xi@(-si);  acc_im = xr@si + xi@sr   (exact i32)
// MODE 0 (QKV, N=3072): col<2048 -> q fp32 planes [tok][2048];
//   2048..2559 -> K bf16 planes [b][kv][s][128]; 2560.. -> V bf16 planes same.
// MODE 1: fp32 planes, stride Nout.
// ---------------------------------------------------------------------------
__device__ __forceinline__ void async_copy16(const void* g, void* l) {
    __builtin_amdgcn_global_load_lds((const __attribute__((address_space(1))) void*)g,
                                     (__attribute__((address_space(3))) void*)l, 16, 0, 0);
}

template <int MODE>
__global__ __launch_bounds__(256)
void gemm_i8_kernel(const int8_t* __restrict__ axr, const int8_t* __restrict__ axi,
                    const int8_t* __restrict__ bsr, const int8_t* __restrict__ bsi,
                    const int8_t* __restrict__ bnsi,
                    int Nout, const float* __restrict__ invs,
                    const float* __restrict__ mag_sums,
                    float magc0, float magc1, float magc2,
                    float* o_re, float* o_im,
                    uint16_t* kbr, uint16_t* kbi, uint16_t* vbr, uint16_t* vbi)
{
    __shared__ alignas(16) int8_t smem[5 * 8192];
    const int tid = threadIdx.x;
    const int wav = tid >> 6, lane = tid & 63;
    const int tileM = blockIdx.y * 128, tileN = blockIdx.x * 128;
    const int wm = wav & 1, wn = wav >> 1;
    const int K = 2048;

    const int8_t* gplane[5] = { axr, axi, bsr, bsi, bnsi };
    const int     rbase[5]  = { tileM, tileM, tileN, tileN, tileN };

    i32x16 acc_re[2][2] = {};
    i32x16 acc_im[2][2] = {};

    for (int k0 = 0; k0 < K; k0 += 64) {
#pragma unroll
        for (int i = 0; i < 10; ++i) {
            int q = wav + 4 * i;            // 40 lds-dma per block-step
            int pl = q >> 3, seg = q & 7;
            int c = seg >> 1, m0 = (seg & 1) << 6;
            const int8_t* g = gplane[pl] + (size_t)(rbase[pl] + m0 + lane) * K + k0 + c * 16;
            int8_t* l = &smem[pl * 8192 + (c * 128 + m0) * 16];
            async_copy16(g, l);
        }
        __syncthreads();
#pragma unroll
        for (int s = 0; s < 2; ++s) {
            const int cc = 2 * s + (lane >> 5);
            const int rA = wm * 64 + (lane & 31);
            const int rB = wn * 64 + (lane & 31);
            i32x4 fxr[2], fxi[2], fsr[2], fsi[2], fns[2];
#pragma unroll
            for (int mb = 0; mb < 2; ++mb) {
                int off = (cc * 128 + rA + mb * 32) * 16;
                fxr[mb] = *(const i32x4*)&smem[0 * 8192 + off];
                fxi[mb] = *(const i32x4*)&smem[1 * 8192 + off];
            }
#pragma unroll
            for (int nb = 0; nb < 2; ++nb) {
                int off = (cc * 128 + rB + nb * 32) * 16;
                fsr[nb] = *(const i32x4*)&smem[2 * 8192 + off];
                fsi[nb] = *(const i32x4*)&smem[3 * 8192 + off];
                fns[nb] = *(const i32x4*)&smem[4 * 8192 + off];
            }
#pragma unroll
            for (int mb = 0; mb < 2; ++mb)
#pragma unroll
                for (int nb = 0; nb < 2; ++nb) {
                    acc_re[mb][nb] = __builtin_amdgcn_mfma_i32_32x32x32_i8(fxr[mb], fsr[nb], acc_re[mb][nb], 0, 0, 0);
                    acc_re[mb][nb] = __builtin_amdgcn_mfma_i32_32x32x32_i8(fxi[mb], fns[nb], acc_re[mb][nb], 0, 0, 0);
                    acc_im[mb][nb] = __builtin_amdgcn_mfma_i32_32x32x32_i8(fxr[mb], fsi[nb], acc_im[mb][nb], 0, 0, 0);
                    acc_im[mb][nb] = __builtin_amdgcn_mfma_i32_32x32x32_i8(fxi[mb], fsr[nb], acc_im[mb][nb], 0, 0, 0);
                }
        }
        __syncthreads();
    }

    const int ln31 = lane & 31, lq = lane >> 5;
#pragma unroll
    for (int mb = 0; mb < 2; ++mb) {
#pragma unroll
        for (int nb = 0; nb < 2; ++nb) {
            const int gn = tileN + wn * 64 + nb * 32 + ln31;
            float mag;
            if (MODE == 0)
                mag = (gn < 2048) ? mag_sums[0] * magc0
                    : (gn < 2560) ? mag_sums[1] * magc1
                                  : mag_sums[2] * magc2;
            else
                mag = mag_sums[0] * magc0;
#pragma unroll
            for (int r = 0; r < 16; ++r) {
                const int row = (r & 3) + 8 * (r >> 2) + 4 * lq;
                const int gm = tileM + wm * 64 + mb * 32 + row;
                const float sc = mag * invs[gm];
                const float re = (float)acc_re[mb][nb][r] * sc;
                const float im = (float)acc_im[mb][nb][r] * sc;
                if (MODE == 1) {
                    o_re[(size_t)gm * Nout + gn] = re;
                    o_im[(size_t)gm * Nout + gn] = im;
                } else {
                    const int s = gm & (S_ - 1), bb = gm >> 10;
                    if (gn < 2048) {
                        o_re[(size_t)gm * 2048 + gn] = re;
                        o_im[(size_t)gm * 2048 + gn] = im;
                    } else if (gn < 2560) {
                        int c = gn - 2048, kvh = c >> 7, d = c & 127;
                        size_t off = ((size_t)(bb * KV_ + kvh) * S_ + s) * 128 + d;
                        kbr[off] = f2bf(re);
                        kbi[off] = f2bf(im);
                    } else {
                        int c = gn - 2560, kvh = c >> 7, d = c & 127;
                        size_t off = ((size_t)(bb * KV_ + kvh) * S_ + s) * 128 + d;
                        vbr[off] = f2bf(re);
                        vbi[off] = f2bf(im);
                    }
                }
            }
        }
    }
}

// ---------------------------------------------------------------------------
// RoPE + bf16 convert + head-major rearrange for Q.
// in: q fp32 [tok][h][128]; out: qb_re (roped) / qb_im bf16 [b][h][s][128].
// thread handles dims d0..d0+3 and d0+64..d0+67 (pairs share freqs).
// ---------------------------------------------------------------------------
__global__ __launch_bounds__(256)
void rope_q_kernel(const float* __restrict__ q_re, const float* __restrict__ q_im,
                   uint16_t* __restrict__ qb_re, uint16_t* __restrict__ qb_im)
{
    int gidx = blockIdx.x * 256 + threadIdx.x;      // tok*256 + h*16 + j
    int j = gidx & 15, h = (gidx >> 4) & 15, tok = gidx >> 8;
    int s = tok & (S_ - 1), b = tok >> 10;
    int d0 = j * 4;
    size_t ib = (size_t)tok * 2048 + h * 128;
    float4 r0 = *(const float4*)&q_re[ib + d0];
    float4 r1 = *(const float4*)&q_re[ib + d0 + 64];
    float4 i0 = *(const float4*)&q_im[ib + d0];
    float4 i1 = *(const float4*)&q_im[ib + d0 + 64];
    float ro0[4], ro1[4];
    float rv0[4] = { r0.x, r0.y, r0.z, r0.w };
    float rv1[4] = { r1.x, r1.y, r1.z, r1.w };
#pragma unroll
    for (int t = 0; t < 4; ++t) {
        float f = __expf(-(float)(d0 + t) * LN1E4_OVER_64);
        float sn, c;
        __sincosf((float)s * f, &sn, &c);
        ro0[t] = rv0[t] * c - rv1[t] * sn;
        ro1[t] = rv1[t] * c + rv0[t] * sn;
    }
    size_t ob = ((size_t)(b * H_ + h) * S_ + s) * 128;
    ushort4 w;
    w = (ushort4){ f2bf(ro0[0]), f2bf(ro0[1]), f2bf(ro0[2]), f2bf(ro0[3]) };
    *(ushort4*)&qb_re[ob + d0] = w;
    w = (ushort4){ f2bf(ro1[0]), f2bf(ro1[1]), f2bf(ro1[2]), f2bf(ro1[3]) };
    *(ushort4*)&qb_re[ob + d0 + 64] = w;
    w = (ushort4){ f2bf(i0.x), f2bf(i0.y), f2bf(i0.z), f2bf(i0.w) };
    *(ushort4*)&qb_im[ob + d0] = w;
    w = (ushort4){ f2bf(i1.x), f2bf(i1.y), f2bf(i1.z), f2bf(i1.w) };
    *(ushort4*)&qb_im[ob + d0 + 64] = w;
}

// RoPE in place on K real bf16 plane [b][kv][s][128].
__global__ __launch_bounds__(256)
void rope_k_kernel(uint16_t* __restrict__ kb_re)
{
    int gidx = blockIdx.x * 256 + threadIdx.x;      // tok*64 + kv*16 + j
    int j = gidx & 15, kvh = (gidx >> 4) & 3;
    int rest = gidx >> 6;
    int s = rest & (S_ - 1), b = rest >> 10;
    int d0 = j * 4;
    size_t base = ((size_t)(b * KV_ + kvh) * S_ + s) * 128;
    ushort4 u0 = *(const ushort4*)&kb_re[base + d0];
    ushort4 u1 = *(const ushort4*)&kb_re[base + d0 + 64];
    float rv0[4] = { bf2f(u0.x), bf2f(u0.y), bf2f(u0.z), bf2f(u0.w) };
    float rv1[4] = { bf2f(u1.x), bf2f(u1.y), bf2f(u1.z), bf2f(u1.w) };
    float ro0[4], ro1[4];
#pragma unroll
    for (int t = 0; t < 4; ++t) {
        float f = __expf(-(float)(d0 + t) * LN1E4_OVER_64);
        float sn, c;
        __sincosf((float)s * f, &sn, &c);
        ro0[t] = rv0[t] * c - rv1[t] * sn;
        ro1[t] = rv1[t] * c + rv0[t] * sn;
    }
    *(ushort4*)&kb_re[base + d0]      = (ushort4){ f2bf(ro0[0]), f2bf(ro0[1]), f2bf(ro0[2]), f2bf(ro0[3]) };
    *(ushort4*)&kb_re[base + d0 + 64] = (ushort4){ f2bf(ro1[0]), f2bf(ro1[1]), f2bf(ro1[2]), f2bf(ro1[3]) };
}

// ---------------------------------------------------------------------------
// V transpose: vb [bk][s][128] bf16 -> vt [bk][d][1024] bf16. 32x32 LDS tiles.
// grid (S/32, 128/32, B*KV*2) — z folds plane.
// ---------------------------------------------------------------------------
__global__ __launch_bounds__(256)
void vtrans_kernel(const uint16_t* __restrict__ vbr, const uint16_t* __restrict__ vbi,
                   uint16_t* __restrict__ vtr, uint16_t* __restrict__ vti)
{
    __shared__ uint16_t t[32][36];
    const int pl = blockIdx.z & 1, bk = blockIdx.z >> 1;
    const int s0 = blockIdx.x * 32, d0 = blockIdx.y * 32;
    const uint16_t* src = (pl ? vbi : vbr) + ((size_t)bk * S_) * 128;
    uint16_t*       dst = (pl ? vti : vtr) + ((size_t)bk * 128) * S_;
    const int r = threadIdx.x >> 3, c = (threadIdx.x & 7) * 4;
    *(ushort4*)&t[r][c] = *(const ushort4*)&src[(size_t)(s0 + r) * 128 + d0 + c];
    __syncthreads();
    ushort4 o = (ushort4){ t[c][r], t[c + 1][r], t[c + 2][r], t[c + 3][r] };
    *(ushort4*)&dst[(size_t)(d0 + r) * S_ + s0 + c] = o;
}

// ---------------------------------------------------------------------------
// MFMA flash attention (bf16 inputs, fp32 accum, online softmax in registers).
// Block: 4 waves x 16 q-rows = 64 rows of one head; K-tiles of 32.
// Q/K frags from [pos][d] row-major; V from transposed [d][pos]; P round-trips
// through per-wave LDS (C-layout -> A-layout). LDS 43 KB -> 3 blocks/CU.
// ---------------------------------------------------------------------------
__global__ __launch_bounds__(256)
void attn_mfma_kernel(const uint16_t* __restrict__ qb_re, const uint16_t* __restrict__ qb_im,
                      const uint16_t* __restrict__ kb_re, const uint16_t* __restrict__ kb_im,
                      const uint16_t* __restrict__ vt_re, const uint16_t* __restrict__ vt_im,
                      float* __restrict__ o_re, float* __restrict__ o_im)
{
    __shared__ alignas(16) uint16_t sk[2][32][136];   // [plane][pos][d] pad->272B rows
    __shared__ alignas(16) uint16_t sv[2][128][40];   // [plane][d][pos] pad->80B rows
    __shared__ alignas(16) uint16_t sp[4][16][40];    // per-wave P, bf16

    const int tid = threadIdx.x;
    const int w = tid >> 6, lane = tid & 63;
    const int r16 = lane & 15, q4 = lane >> 4;
    const int qt = gridDim.x - 1 - blockIdx.x;        // heavy blocks dispatch first
    const int h = blockIdx.y, b = blockIdx.z;
    const int kvh = h >> 2;
    const int q0 = qt * 64, qw0 = q0 + w * 16;

    // Q fragments (A-operand): rows qw0+r16, all 128 dims (4 k-steps), re+im
    bf16x8 qfr[4], qfi[4];
    {
        const size_t qbase = ((size_t)(b * H_ + h) * S_ + qw0 + r16) * 128;
#pragma unroll
        for (int ks = 0; ks < 4; ++ks) {
            const int col = ks * 32 + q4 * 8;
            qfr[ks] = *(const bf16x8*)&qb_re[qbase + col];
            qfi[ks] = *(const bf16x8*)&qb_im[qbase + col];
        }
    }

    f32x4 oa[2][8] = {};                      // [plane][dblk] C-layout accum
    float m_r[4] = { -3e38f, -3e38f, -3e38f, -3e38f };
    float l_r[4] = { 0.f, 0.f, 0.f, 0.f };

    const size_t kgbase0 = (size_t)(b * KV_ + kvh) * S_ * 128;
    const size_t vgbase0 = (size_t)(b * KV_ + kvh) * 128 * (size_t)S_;

    for (int c0 = 0; c0 < q0 + 64; c0 += 32) {
        // ---- stage K tile [32][128] re+im ----
        for (int idx = tid; idx < 1024; idx += 256) {
            int pl = idx >> 9, c = idx & 511, r = c >> 4, ch = c & 15;
            const uint16_t* src = (pl ? kb_im : kb_re) + kgbase0 + (size_t)(c0 + r) * 128 + ch * 8;
            *(uint4*)&sk[pl][r][ch * 8] = *(const uint4*)src;
        }
        // ---- stage V^T tile [128][32] re+im ----
        for (int idx = tid; idx < 1024; idx += 256) {
            int pl = idx >> 9, c = idx & 511, d = c >> 2, ch = c & 3;
            const uint16_t* src = (pl ? vt_im : vt_re) + vgbase0 + (size_t)d * S_ + c0 + ch * 8;
            *(uint4*)&sv[pl][d][ch * 8] = *(const uint4*)src;
        }
        __syncthreads();

        if (c0 <= qw0 + 15) {                 // wave has unmasked work here
            // ---- scores: 2 col-blocks of 16 ----
            f32x4 sc[2] = {};
#pragma unroll
            for (int cblk = 0; cblk < 2; ++cblk) {
                const int krow = cblk * 16 + r16;
#pragma unroll
                for (int ks = 0; ks < 4; ++ks) {
                    const int kcol = ks * 32 + q4 * 8;
                    bf16x8 kr = *(const bf16x8*)&sk[0][krow][kcol];
                    bf16x8 ki = *(const bf16x8*)&sk[1][krow][kcol];
                    sc[cblk] = __builtin_amdgcn_mfma_f32_16x16x32_bf16(qfr[ks], kr, sc[cblk], 0, 0, 0);
                    sc[cblk] = __builtin_amdgcn_mfma_f32_16x16x32_bf16(qfi[ks], ki, sc[cblk], 0, 0, 0);
                }
            }
            // scale + causal mask (C-layout: row=q4*4+reg, col=r16)
#pragma unroll
            for (int cblk = 0; cblk < 2; ++cblk)
#pragma unroll
                for (int reg = 0; reg < 4; ++reg) {
                    float sval = sc[cblk][reg] * 0.08838834764831845f;
                    const int rowg = qw0 + q4 * 4 + reg;
                    const int colg = c0 + cblk * 16 + r16;
                    if (colg > rowg) sval = -3e38f;
                    sc[cblk][reg] = sval;
                }
            // ---- online softmax (16-lane shuffle groups) ----
            float al[4];
#pragma unroll
            for (int reg = 0; reg < 4; ++reg) {
                float mx = fmaxf(sc[0][reg], sc[1][reg]);
#pragma unroll
                for (int msk = 1; msk < 16; msk <<= 1) mx = fmaxf(mx, __shfl_xor(mx, msk));
                const float mn = fmaxf(m_r[reg], mx);
                al[reg] = __expf(m_r[reg] - mn);
                const float p0 = __expf(sc[0][reg] - mn);
                const float p1 = __expf(sc[1][reg] - mn);
                sc[0][reg] = p0; sc[1][reg] = p1;
                float rs = p0 + p1;
#pragma unroll
                for (int msk = 1; msk < 16; msk <<= 1) rs += __shfl_xor(rs, msk);
                l_r[reg] = l_r[reg] * al[reg] + rs;
                m_r[reg] = mn;
            }
            // ---- P: C-layout -> LDS (bf16) ----
#pragma unroll
            for (int cblk = 0; cblk < 2; ++cblk)
#pragma unroll
                for (int reg = 0; reg < 4; ++reg)
                    sp[w][q4 * 4 + reg][cblk * 16 + r16] = f2bf(sc[cblk][reg]);
            // ---- rescale O ----
#pragma unroll
            for (int dblk = 0; dblk < 8; ++dblk)
#pragma unroll
                for (int reg = 0; reg < 4; ++reg) {
                    oa[0][dblk][reg] *= al[reg];
                    oa[1][dblk][reg] *= al[reg];
                }
            // ---- PV: A = P (from own LDS region), B = V^T slices ----
            bf16x8 pf = *(const bf16x8*)&sp[w][r16][q4 * 8];
#pragma unroll
            for (int dblk = 0; dblk < 8; ++dblk) {
                const int vrow = dblk * 16 + r16;
                bf16x8 vr = *(const bf16x8*)&sv[0][vrow][q4 * 8];
                bf16x8 vi = *(const bf16x8*)&sv[1][vrow][q4 * 8];
                oa[0][dblk] = __builtin_amdgcn_mfma_f32_16x16x32_bf16(pf, vr, oa[0][dblk], 0, 0, 0);
                oa[1][dblk] = __builtin_amdgcn_mfma_f32_16x16x32_bf16(pf, vi, oa[1][dblk], 0, 0, 0);
            }
        }
        __syncthreads();
    }

    float inv[4];
#pragma unroll
    for (int reg = 0; reg < 4; ++reg) inv[reg] = 1.f / l_r[reg];
#pragma unroll
    for (int dblk = 0; dblk < 8; ++dblk) {
        const int col = h * 128 + dblk * 16 + r16;
#pragma unroll
        for (int reg = 0; reg < 4; ++reg) {
            const size_t tok = (size_t)b * S_ + qw0 + q4 * 4 + reg;
            o_re[tok * 2048 + col] = oa[0][dblk][reg] * inv[reg];
            o_im[tok * 2048 + col] = oa[1][dblk][reg] * inv[reg];
        }
    }
}

// ---------------------------------------------------------------------------
extern "C" void kernel_launch(void* const* d_in, const int* in_sizes, int n_in,
                              void* d_out, int out_size, void* d_ws, size_t ws_size,
                              hipStream_t stream)
{
    const float* hr    = (const float*)d_in[0];
    const float* hi    = (const float*)d_in[1];
    const float* wq_re = (const float*)d_in[2];
    const float* wq_im = (const float*)d_in[3];
    const float* wk_re = (const float*)d_in[4];
    const float* wk_im = (const float*)d_in[5];
    const float* wv_re = (const float*)d_in[6];
    const float* wv_im = (const float*)d_in[7];
    const float* wo_re = (const float*)d_in[8];
    const float* wo_im = (const float*)d_in[9];
    float* out = (float*)d_out;
    char*  base = (char*)d_ws;

    const size_t MB4  = (size_t)2048 * 2048;        // 4 MB int8 plane
    const size_t QKVP = (size_t)3072 * 2048;        // 6.29 MB int8 plane
    const size_t KVE  = (size_t)B_ * KV_ * S_ * 128; // 1M bf16 elements

    float*   mags   = (float*)(base);               // 4 floats, zeroed
    float*   invs1  = (float*)(base + 1024);
    float*   invs2  = (float*)(base + 9216);
    int8_t*  xr_q   = (int8_t*)(base + 32768);
    int8_t*  xi_q   = xr_q + MB4;
    int8_t*  qkv_sr = xi_q + MB4;
    int8_t*  qkv_si = qkv_sr + QKVP;
    int8_t*  qkv_ns = qkv_si + QKVP;
    int8_t*  wo_sr  = qkv_ns + QKVP;
    int8_t*  wo_si  = wo_sr + MB4;
    int8_t*  wo_ns  = wo_si + MB4;
    float*   q_re   = (float*)(wo_ns + MB4);        // fp32 [tok][2048]; reused as o
    float*   q_im   = q_re + MB4;
    uint16_t* kb_re = (uint16_t*)(q_im + MB4);      // bf16 [b][kv][s][128]
    uint16_t* kb_im = kb_re + KVE;
    uint16_t* vb_re = kb_im + KVE;
    uint16_t* vb_im = vb_re + KVE;
    // aliases (lifetimes verified against stream order):
    uint16_t* vt_re = (uint16_t*)xr_q;              // written after QKV GEMM consumed xr_q
    uint16_t* vt_im = (uint16_t*)xi_q;
    uint16_t* qb_re = (uint16_t*)qkv_sr;            // written after QKV GEMM consumed signs
    uint16_t* qb_im = (uint16_t*)(qkv_sr + 8388608);

    hipMemsetAsync(mags, 0, 16, stream);

    // decode weights (fused mag reduction)
    decode_kernel<<<dim3(32, 32), 256, 0, stream>>>(wq_re, wq_im, 2048, qkv_sr, qkv_si, qkv_ns, 0,    mags + 0);
    decode_kernel<<<dim3(8, 32),  256, 0, stream>>>(wk_re, wk_im, 512,  qkv_sr, qkv_si, qkv_ns, 2048, mags + 1);
    decode_kernel<<<dim3(8, 32),  256, 0, stream>>>(wv_re, wv_im, 512,  qkv_sr, qkv_si, qkv_ns, 2560, mags + 2);
    decode_kernel<<<dim3(32, 32), 256, 0, stream>>>(wo_re, wo_im, 2048, wo_sr, wo_si, wo_ns, 0,       mags + 3);

    act_quant_i8_kernel<<<NTOK, 256, 0, stream>>>(hr, hi, xr_q, xi_q, invs1);

    gemm_i8_kernel<0><<<dim3(24, 16), 256, 0, stream>>>(
        xr_q, xi_q, qkv_sr, qkv_si, qkv_ns, 0, invs1, mags,
        1.0f / (float)((size_t)D_ * QD), 1.0f / (float)((size_t)D_ * KD), 1.0f / (float)((size_t)D_ * KD),
        q_re, q_im, kb_re, kb_im, vb_re, vb_im);

    rope_q_kernel<<<NTOK * H_ * 16 / 256, 256, 0, stream>>>(q_re, q_im, qb_re, qb_im);
    rope_k_kernel<<<NTOK * KV_ * 16 / 256, 256, 0, stream>>>(kb_re);
    vtrans_kernel<<<dim3(S_ / 32, 128 / 32, B_ * KV_ * 2), 256, 0, stream>>>(vb_re, vb_im, vt_re, vt_im);

    attn_mfma_kernel<<<dim3(S_ / 64, H_, B_), 256, 0, stream>>>(
        qb_re, qb_im, kb_re, kb_im, vt_re, vt_im, q_re, q_im);

    act_quant_i8_kernel<<<NTOK, 256, 0, stream>>>(q_re, q_im, xr_q, xi_q, invs2);

    gemm_i8_kernel<1><<<dim3(16, 16), 256, 0, stream>>>(
        xr_q, xi_q, wo_sr, wo_si, wo_ns, 2048, invs2, mags + 3,
        1.0f / (float)((size_t)QD * D_), 0.f, 0.f,
        out, out + MB4, nullptr, nullptr, nullptr, nullptr);
}

// Round 5
// 533.531 us; speedup vs baseline: 9.5803x; 1.1222x over previous
//
#include <hip/hip_runtime.h>
#include <stdint.h>

#define B_   2
#define S_   1024
#define D_   2048
#define H_   16
#define KV_  4
#define HD_  128
#define NTOK (B_ * S_)        /* 2048 tokens */
#define QD   (H_ * HD_)       /* 2048 */
#define KD   (KV_ * HD_)      /* 512  */

using i32x4  = __attribute__((ext_vector_type(4)))  int;
using i32x16 = __attribute__((ext_vector_type(16))) int;
using f32x4  = __attribute__((ext_vector_type(4)))  float;
using bf16x8 = __attribute__((ext_vector_type(8)))  short;

#define LN1E4_OVER_64 0.14391156831212725f

// ---------------- bf16 helpers ---------------------------------------------
__device__ __forceinline__ float bf2f(uint16_t u) { return __uint_as_float((uint32_t)u << 16); }
__device__ __forceinline__ uint16_t f2bf(float f) {
    uint32_t u = __float_as_uint(f);
    return (uint16_t)((u + 0x7FFFu + ((u >> 16) & 1u)) >> 16);   // RNE
}

// ---------------------------------------------------------------------------
// Per-token joint absmax int8 quantization (dim = 2048 fixed).
// ---------------------------------------------------------------------------
__global__ __launch_bounds__(256)
void act_quant_i8_kernel(const float* __restrict__ xr, const float* __restrict__ xi,
                         int8_t* __restrict__ qr, int8_t* __restrict__ qi,
                         float* __restrict__ invs)
{
    const int tok = blockIdx.x, t = threadIdx.x;
    const float* pr = xr + (size_t)tok * 2048 + t * 8;
    const float* pi = xi + (size_t)tok * 2048 + t * 8;
    float4 r0 = *(const float4*)pr, r1 = *(const float4*)(pr + 4);
    float4 i0 = *(const float4*)pi, i1 = *(const float4*)(pi + 4);
    float am = fmaxf(fmaxf(fmaxf(fabsf(r0.x), fabsf(r0.y)), fmaxf(fabsf(r0.z), fabsf(r0.w))),
                     fmaxf(fmaxf(fabsf(r1.x), fabsf(r1.y)), fmaxf(fabsf(r1.z), fabsf(r1.w))));
    am = fmaxf(am, fmaxf(fmaxf(fmaxf(fabsf(i0.x), fabsf(i0.y)), fmaxf(fabsf(i0.z), fabsf(i0.w))),
                         fmaxf(fmaxf(fabsf(i1.x), fabsf(i1.y)), fmaxf(fabsf(i1.z), fabsf(i1.w)))));
    __shared__ float red[256];
    red[t] = am;
    __syncthreads();
    for (int st = 128; st > 0; st >>= 1) {
        if (t < st) red[t] = fmaxf(red[t], red[t + st]);
        __syncthreads();
    }
    const float s = 127.0f / fmaxf(red[0], 1e-5f);
    if (t == 0) invs[tok] = 1.0f / s;
#define Q8(x) ((uint32_t)(uint8_t)(int8_t)(int)fminf(fmaxf(rintf((x) * s), -128.f), 127.f))
    uint32_t a0 = Q8(r0.x) | (Q8(r0.y) << 8) | (Q8(r0.z) << 16) | (Q8(r0.w) << 24);
    uint32_t a1 = Q8(r1.x) | (Q8(r1.y) << 8) | (Q8(r1.z) << 16) | (Q8(r1.w) << 24);
    uint32_t b0 = Q8(i0.x) | (Q8(i0.y) << 8) | (Q8(i0.z) << 16) | (Q8(i0.w) << 24);
    uint32_t b1 = Q8(i1.x) | (Q8(i1.y) << 8) | (Q8(i1.z) << 16) | (Q8(i1.w) << 24);
#undef Q8
    *(uint32_t*)(qr + (size_t)tok * 2048 + t * 8)     = a0;
    *(uint32_t*)(qr + (size_t)tok * 2048 + t * 8 + 4) = a1;
    *(uint32_t*)(qi + (size_t)tok * 2048 + t * 8)     = b0;
    *(uint32_t*)(qi + (size_t)tok * 2048 + t * 8 + 4) = b1;
}

// ---------------------------------------------------------------------------
// Weight decode + transpose + fused mag reduction.
// ---------------------------------------------------------------------------
__global__ __launch_bounds__(256)
void decode_kernel(const float* __restrict__ wr, const float* __restrict__ wi,
                   int N, int8_t* __restrict__ psr, int8_t* __restrict__ psi,
                   int8_t* __restrict__ pnsi, int n_off, float* __restrict__ mag_out)
{
    __shared__ alignas(16) int8_t tr[3][64][80];
    __shared__ float red[256];
    const int n0 = blockIdx.x * 64, k0 = blockIdx.y * 64;
    float msum = 0.f;
    for (int idx = threadIdx.x; idx < 4096; idx += 256) {
        int j = idx & 63, i = idx >> 6;                 // j = n, i = k
        size_t g = (size_t)(k0 + i) * N + n0 + j;
        float a = wr[g], b = wi[g];
        msum += sqrtf(a * a + b * b);
        int8_t sr, si;
        if (fabsf(a) >= fabsf(b)) {
            sr = (a > 0.f) ? 1 : ((a < 0.f) ? -1 : 0);
            si = 0;
        } else {
            sr = 0;
            si = (b > 0.f) ? 1 : ((b < 0.f) ? -1 : 0);
        }
        tr[0][j][i] = sr;
        tr[1][j][i] = si;
        tr[2][j][i] = (int8_t)(-si);
    }
    red[threadIdx.x] = msum;
    __syncthreads();
    for (int st = 128; st > 0; st >>= 1) {
        if (threadIdx.x < st) red[threadIdx.x] += red[threadIdx.x + st];
        __syncthreads();
    }
    if (threadIdx.x == 0) atomicAdd(mag_out, red[0]);
    int8_t* planes[3] = { psr, psi, pnsi };
    for (int idx = threadIdx.x; idx < 768; idx += 256) {
        int p = idx >> 8, rem = idx & 255, n = rem >> 2, c = rem & 3;
        int4 v = *(const int4*)&tr[p][n][c * 16];
        *(int4*)(planes[p] + (size_t)(n_off + n0 + n) * 2048 + k0 + c * 16) = v;
    }
}

// ---------------------------------------------------------------------------
// int8 MFMA complex GEMM — double-buffered LDS pipeline with raw s_barrier +
// partial vmcnt waits. Each wave owns exactly 10 global_load_lds per tile;
// vmcnt(10) == "previous tile complete, next tile in flight". Tile k+1 DMA
// overlaps tile k MFMA — the drain-free K-loop the 2-barrier shape can't do.
// ---------------------------------------------------------------------------
__device__ __forceinline__ void async_copy16(const void* g, void* l) {
    __builtin_amdgcn_global_load_lds((const __attribute__((address_space(1))) void*)g,
                                     (__attribute__((address_space(3))) void*)l, 16, 0, 0);
}

template <int MODE>
__global__ __launch_bounds__(256)
void gemm_i8_kernel(const int8_t* __restrict__ axr, const int8_t* __restrict__ axi,
                    const int8_t* __restrict__ bsr, const int8_t* __restrict__ bsi,
                    const int8_t* __restrict__ bnsi,
                    int Nout, const float* __restrict__ invs,
                    const float* __restrict__ mag_sums,
                    float magc0, float magc1, float magc2,
                    float* o_re, float* o_im,
                    uint16_t* kbr, uint16_t* kbi, uint16_t* vbr, uint16_t* vbi)
{
    __shared__ alignas(16) int8_t smem[2][5 * 8192];   // 80 KB, 2-stage
    const int tid = threadIdx.x;
    const int wav = tid >> 6, lane = tid & 63;
    const int tileM = blockIdx.y * 128, tileN = blockIdx.x * 128;
    const int wm = wav & 1, wn = wav >> 1;
    const int K = 2048;

    const int8_t* gplane[5] = { axr, axi, bsr, bsi, bnsi };
    const int     rbase[5]  = { tileM, tileM, tileN, tileN, tileN };

    i32x16 acc_re[2][2] = {};
    i32x16 acc_im[2][2] = {};

    auto issue_tile = [&](int k0, int buf) {
#pragma unroll
        for (int i = 0; i < 10; ++i) {
            int q = wav + 4 * i;            // 40 lds-dma per tile, 10 per wave
            int pl = q >> 3, seg = q & 7;
            int c = seg >> 1, m0 = (seg & 1) << 6;
            const int8_t* g = gplane[pl] + (size_t)(rbase[pl] + m0 + lane) * K + k0 + c * 16;
            int8_t* l = &smem[buf][pl * 8192 + (c * 128 + m0) * 16];
            async_copy16(g, l);
        }
    };

    issue_tile(0, 0);
    issue_tile(64, 1);

    for (int k = 0; k < 32; ++k) {
        if (k == 31) { asm volatile("s_waitcnt vmcnt(0)" ::: "memory"); }
        else         { asm volatile("s_waitcnt vmcnt(10)" ::: "memory"); }
        asm volatile("s_barrier" ::: "memory");
        const int8_t* sb = smem[k & 1];
#pragma unroll
        for (int s = 0; s < 2; ++s) {
            const int cc = 2 * s + (lane >> 5);
            const int rA = wm * 64 + (lane & 31);
            const int rB = wn * 64 + (lane & 31);
            i32x4 fxr[2], fxi[2], fsr[2], fsi[2], fns[2];
#pragma unroll
            for (int mb = 0; mb < 2; ++mb) {
                int off = (cc * 128 + rA + mb * 32) * 16;
                fxr[mb] = *(const i32x4*)&sb[0 * 8192 + off];
                fxi[mb] = *(const i32x4*)&sb[1 * 8192 + off];
            }
#pragma unroll
            for (int nb = 0; nb < 2; ++nb) {
                int off = (cc * 128 + rB + nb * 32) * 16;
                fsr[nb] = *(const i32x4*)&sb[2 * 8192 + off];
                fsi[nb] = *(const i32x4*)&sb[3 * 8192 + off];
                fns[nb] = *(const i32x4*)&sb[4 * 8192 + off];
            }
#pragma unroll
            for (int mb = 0; mb < 2; ++mb)
#pragma unroll
                for (int nb = 0; nb < 2; ++nb) {
                    acc_re[mb][nb] = __builtin_amdgcn_mfma_i32_32x32x32_i8(fxr[mb], fsr[nb], acc_re[mb][nb], 0, 0, 0);
                    acc_re[mb][nb] = __builtin_amdgcn_mfma_i32_32x32x32_i8(fxi[mb], fns[nb], acc_re[mb][nb], 0, 0, 0);
                    acc_im[mb][nb] = __builtin_amdgcn_mfma_i32_32x32x32_i8(fxr[mb], fsi[nb], acc_im[mb][nb], 0, 0, 0);
                    acc_im[mb][nb] = __builtin_amdgcn_mfma_i32_32x32x32_i8(fxi[mb], fsr[nb], acc_im[mb][nb], 0, 0, 0);
                }
        }
        asm volatile("s_barrier" ::: "memory");       // all reads of buf done
        if (k + 2 < 32) issue_tile((k + 2) * 64, k & 1);
    }

    const int ln31 = lane & 31, lq = lane >> 5;
#pragma unroll
    for (int mb = 0; mb < 2; ++mb) {
#pragma unroll
        for (int nb = 0; nb < 2; ++nb) {
            const int gn = tileN + wn * 64 + nb * 32 + ln31;
            float mag;
            if (MODE == 0)
                mag = (gn < 2048) ? mag_sums[0] * magc0
                    : (gn < 2560) ? mag_sums[1] * magc1
                                  : mag_sums[2] * magc2;
            else
                mag = mag_sums[0] * magc0;
#pragma unroll
            for (int r = 0; r < 16; ++r) {
                const int row = (r & 3) + 8 * (r >> 2) + 4 * lq;
                const int gm = tileM + wm * 64 + mb * 32 + row;
                const float sc = mag * invs[gm];
                const float re = (float)acc_re[mb][nb][r] * sc;
                const float im = (float)acc_im[mb][nb][r] * sc;
                if (MODE == 1) {
                    o_re[(size_t)gm * Nout + gn] = re;
                    o_im[(size_t)gm * Nout + gn] = im;
                } else {
                    const int s = gm & (S_ - 1), bb = gm >> 10;
                    if (gn < 2048) {
                        o_re[(size_t)gm * 2048 + gn] = re;
                        o_im[(size_t)gm * 2048 + gn] = im;
                    } else if (gn < 2560) {
                        int c = gn - 2048, kvh = c >> 7, d = c & 127;
                        size_t off = ((size_t)(bb * KV_ + kvh) * S_ + s) * 128 + d;
                        kbr[off] = f2bf(re);
                        kbi[off] = f2bf(im);
                    } else {
                        int c = gn - 2560, kvh = c >> 7, d = c & 127;
                        size_t off = ((size_t)(bb * KV_ + kvh) * S_ + s) * 128 + d;
                        vbr[off] = f2bf(re);
                        vbi[off] = f2bf(im);
                    }
                }
            }
        }
    }
}

// ---------------------------------------------------------------------------
// RoPE + bf16 convert + head-major rearrange for Q.
// ---------------------------------------------------------------------------
__global__ __launch_bounds__(256)
void rope_q_kernel(const float* __restrict__ q_re, const float* __restrict__ q_im,
                   uint16_t* __restrict__ qb_re, uint16_t* __restrict__ qb_im)
{
    int gidx = blockIdx.x * 256 + threadIdx.x;      // tok*256 + h*16 + j
    int j = gidx & 15, h = (gidx >> 4) & 15, tok = gidx >> 8;
    int s = tok & (S_ - 1), b = tok >> 10;
    int d0 = j * 4;
    size_t ib = (size_t)tok * 2048 + h * 128;
    float4 r0 = *(const float4*)&q_re[ib + d0];
    float4 r1 = *(const float4*)&q_re[ib + d0 + 64];
    float4 i0 = *(const float4*)&q_im[ib + d0];
    float4 i1 = *(const float4*)&q_im[ib + d0 + 64];
    float ro0[4], ro1[4];
    float rv0[4] = { r0.x, r0.y, r0.z, r0.w };
    float rv1[4] = { r1.x, r1.y, r1.z, r1.w };
#pragma unroll
    for (int t = 0; t < 4; ++t) {
        float f = __expf(-(float)(d0 + t) * LN1E4_OVER_64);
        float sn, c;
        __sincosf((float)s * f, &sn, &c);
        ro0[t] = rv0[t] * c - rv1[t] * sn;
        ro1[t] = rv1[t] * c + rv0[t] * sn;
    }
    size_t ob = ((size_t)(b * H_ + h) * S_ + s) * 128;
    ushort4 w;
    w = (ushort4){ f2bf(ro0[0]), f2bf(ro0[1]), f2bf(ro0[2]), f2bf(ro0[3]) };
    *(ushort4*)&qb_re[ob + d0] = w;
    w = (ushort4){ f2bf(ro1[0]), f2bf(ro1[1]), f2bf(ro1[2]), f2bf(ro1[3]) };
    *(ushort4*)&qb_re[ob + d0 + 64] = w;
    w = (ushort4){ f2bf(i0.x), f2bf(i0.y), f2bf(i0.z), f2bf(i0.w) };
    *(ushort4*)&qb_im[ob + d0] = w;
    w = (ushort4){ f2bf(i1.x), f2bf(i1.y), f2bf(i1.z), f2bf(i1.w) };
    *(ushort4*)&qb_im[ob + d0 + 64] = w;
}

// RoPE in place on K real bf16 plane [b][kv][s][128].
__global__ __launch_bounds__(256)
void rope_k_kernel(uint16_t* __restrict__ kb_re)
{
    int gidx = blockIdx.x * 256 + threadIdx.x;
    int j = gidx & 15, kvh = (gidx >> 4) & 3;
    int rest = gidx >> 6;
    int s = rest & (S_ - 1), b = rest >> 10;
    int d0 = j * 4;
    size_t base = ((size_t)(b * KV_ + kvh) * S_ + s) * 128;
    ushort4 u0 = *(const ushort4*)&kb_re[base + d0];
    ushort4 u1 = *(const ushort4*)&kb_re[base + d0 + 64];
    float rv0[4] = { bf2f(u0.x), bf2f(u0.y), bf2f(u0.z), bf2f(u0.w) };
    float rv1[4] = { bf2f(u1.x), bf2f(u1.y), bf2f(u1.z), bf2f(u1.w) };
    float ro0[4], ro1[4];
#pragma unroll
    for (int t = 0; t < 4; ++t) {
        float f = __expf(-(float)(d0 + t) * LN1E4_OVER_64);
        float sn, c;
        __sincosf((float)s * f, &sn, &c);
        ro0[t] = rv0[t] * c - rv1[t] * sn;
        ro1[t] = rv1[t] * c + rv0[t] * sn;
    }
    *(ushort4*)&kb_re[base + d0]      = (ushort4){ f2bf(ro0[0]), f2bf(ro0[1]), f2bf(ro0[2]), f2bf(ro0[3]) };
    *(ushort4*)&kb_re[base + d0 + 64] = (ushort4){ f2bf(ro1[0]), f2bf(ro1[1]), f2bf(ro1[2]), f2bf(ro1[3]) };
}

// ---------------------------------------------------------------------------
// V transpose: vb [bk][s][128] bf16 -> vt [bk][d][1024] bf16.
// ---------------------------------------------------------------------------
__global__ __launch_bounds__(256)
void vtrans_kernel(const uint16_t* __restrict__ vbr, const uint16_t* __restrict__ vbi,
                   uint16_t* __restrict__ vtr, uint16_t* __restrict__ vti)
{
    __shared__ uint16_t t[32][36];
    const int pl = blockIdx.z & 1, bk = blockIdx.z >> 1;
    const int s0 = blockIdx.x * 32, d0 = blockIdx.y * 32;
    const uint16_t* src = (pl ? vbi : vbr) + ((size_t)bk * S_) * 128;
    uint16_t*       dst = (pl ? vti : vtr) + ((size_t)bk * 128) * S_;
    const int r = threadIdx.x >> 3, c = (threadIdx.x & 7) * 4;
    *(ushort4*)&t[r][c] = *(const ushort4*)&src[(size_t)(s0 + r) * 128 + d0 + c];
    __syncthreads();
    ushort4 o = (ushort4){ t[c][r], t[c + 1][r], t[c + 2][r], t[c + 3][r] };
    *(ushort4*)&dst[(size_t)(d0 + r) * S_ + s0 + c] = o;
}

// ---------------------------------------------------------------------------
// MFMA flash attention (bf16, fp32 accum, online softmax in registers).
// ---------------------------------------------------------------------------
__global__ __launch_bounds__(256)
void attn_mfma_kernel(const uint16_t* __restrict__ qb_re, const uint16_t* __restrict__ qb_im,
                      const uint16_t* __restrict__ kb_re, const uint16_t* __restrict__ kb_im,
                      const uint16_t* __restrict__ vt_re, const uint16_t* __restrict__ vt_im,
                      float* __restrict__ o_re, float* __restrict__ o_im)
{
    __shared__ alignas(16) uint16_t sk[2][32][136];
    __shared__ alignas(16) uint16_t sv[2][128][40];
    __shared__ alignas(16) uint16_t sp[4][16][40];

    const int tid = threadIdx.x;
    const int w = tid >> 6, lane = tid & 63;
    const int r16 = lane & 15, q4 = lane >> 4;
    const int qt = gridDim.x - 1 - blockIdx.x;        // heavy blocks dispatch first
    const int h = blockIdx.y, b = blockIdx.z;
    const int kvh = h >> 2;
    const int q0 = qt * 64, qw0 = q0 + w * 16;

    bf16x8 qfr[4], qfi[4];
    {
        const size_t qbase = ((size_t)(b * H_ + h) * S_ + qw0 + r16) * 128;
#pragma unroll
        for (int ks = 0; ks < 4; ++ks) {
            const int col = ks * 32 + q4 * 8;
            qfr[ks] = *(const bf16x8*)&qb_re[qbase + col];
            qfi[ks] = *(const bf16x8*)&qb_im[qbase + col];
        }
    }

    f32x4 oa[2][8] = {};
    float m_r[4] = { -3e38f, -3e38f, -3e38f, -3e38f };
    float l_r[4] = { 0.f, 0.f, 0.f, 0.f };

    const size_t kgbase0 = (size_t)(b * KV_ + kvh) * S_ * 128;
    const size_t vgbase0 = (size_t)(b * KV_ + kvh) * 128 * (size_t)S_;

    for (int c0 = 0; c0 < q0 + 64; c0 += 32) {
        for (int idx = tid; idx < 1024; idx += 256) {
            int pl = idx >> 9, c = idx & 511, r = c >> 4, ch = c & 15;
            const uint16_t* src = (pl ? kb_im : kb_re) + kgbase0 + (size_t)(c0 + r) * 128 + ch * 8;
            *(uint4*)&sk[pl][r][ch * 8] = *(const uint4*)src;
        }
        for (int idx = tid; idx < 1024; idx += 256) {
            int pl = idx >> 9, c = idx & 511, d = c >> 2, ch = c & 3;
            const uint16_t* src = (pl ? vt_im : vt_re) + vgbase0 + (size_t)d * S_ + c0 + ch * 8;
            *(uint4*)&sv[pl][d][ch * 8] = *(const uint4*)src;
        }
        __syncthreads();

        if (c0 <= qw0 + 15) {
            f32x4 sc[2] = {};
#pragma unroll
            for (int cblk = 0; cblk < 2; ++cblk) {
                const int krow = cblk * 16 + r16;
#pragma unroll
                for (int ks = 0; ks < 4; ++ks) {
                    const int kcol = ks * 32 + q4 * 8;
                    bf16x8 kr = *(const bf16x8*)&sk[0][krow][kcol];
                    bf16x8 ki = *(const bf16x8*)&sk[1][krow][kcol];
                    sc[cblk] = __builtin_amdgcn_mfma_f32_16x16x32_bf16(qfr[ks], kr, sc[cblk], 0, 0, 0);
                    sc[cblk] = __builtin_amdgcn_mfma_f32_16x16x32_bf16(qfi[ks], ki, sc[cblk], 0, 0, 0);
                }
            }
#pragma unroll
            for (int cblk = 0; cblk < 2; ++cblk)
#pragma unroll
                for (int reg = 0; reg < 4; ++reg) {
                    float sval = sc[cblk][reg] * 0.08838834764831845f;
                    const int rowg = qw0 + q4 * 4 + reg;
                    const int colg = c0 + cblk * 16 + r16;
                    if (colg > rowg) sval = -3e38f;
                    sc[cblk][reg] = sval;
                }
            float al[4];
#pragma unroll
            for (int reg = 0; reg < 4; ++reg) {
                float mx = fmaxf(sc[0][reg], sc[1][reg]);
#pragma unroll
                for (int msk = 1; msk < 16; msk <<= 1) mx = fmaxf(mx, __shfl_xor(mx, msk));
                const float mn = fmaxf(m_r[reg], mx);
                al[reg] = __expf(m_r[reg] - mn);
                const float p0 = __expf(sc[0][reg] - mn);
                const float p1 = __expf(sc[1][reg] - mn);
                sc[0][reg] = p0; sc[1][reg] = p1;
                float rs = p0 + p1;
#pragma unroll
                for (int msk = 1; msk < 16; msk <<= 1) rs += __shfl_xor(rs, msk);
                l_r[reg] = l_r[reg] * al[reg] + rs;
                m_r[reg] = mn;
            }
#pragma unroll
            for (int cblk = 0; cblk < 2; ++cblk)
#pragma unroll
                for (int reg = 0; reg < 4; ++reg)
                    sp[w][q4 * 4 + reg][cblk * 16 + r16] = f2bf(sc[cblk][reg]);
#pragma unroll
            for (int dblk = 0; dblk < 8; ++dblk)
#pragma unroll
                for (int reg = 0; reg < 4; ++reg) {
                    oa[0][dblk][reg] *= al[reg];
                    oa[1][dblk][reg] *= al[reg];
                }
            bf16x8 pf = *(const bf16x8*)&sp[w][r16][q4 * 8];
#pragma unroll
            for (int dblk = 0; dblk < 8; ++dblk) {
                const int vrow = dblk * 16 + r16;
                bf16x8 vr = *(const bf16x8*)&sv[0][vrow][q4 * 8];
                bf16x8 vi = *(const bf16x8*)&sv[1][vrow][q4 * 8];
                oa[0][dblk] = __builtin_amdgcn_mfma_f32_16x16x32_bf16(pf, vr, oa[0][dblk], 0, 0, 0);
                oa[1][dblk] = __builtin_amdgcn_mfma_f32_16x16x32_bf16(pf, vi, oa[1][dblk], 0, 0, 0);
            }
        }
        __syncthreads();
    }

    float inv[4];
#pragma unroll
    for (int reg = 0; reg < 4; ++reg) inv[reg] = 1.f / l_r[reg];
#pragma unroll
    for (int dblk = 0; dblk < 8; ++dblk) {
        const int col = h * 128 + dblk * 16 + r16;
#pragma unroll
        for (int reg = 0; reg < 4; ++reg) {
            const size_t tok = (size_t)b * S_ + qw0 + q4 * 4 + reg;
            o_re[tok * 2048 + col] = oa[0][dblk][reg] * inv[reg];
            o_im[tok * 2048 + col] = oa[1][dblk][reg] * inv[reg];
        }
    }
}

// ---------------------------------------------------------------------------
extern "C" void kernel_launch(void* const* d_in, const int* in_sizes, int n_in,
                              void* d_out, int out_size, void* d_ws, size_t ws_size,
                              hipStream_t stream)
{
    const float* hr    = (const float*)d_in[0];
    const float* hi    = (const float*)d_in[1];
    const float* wq_re = (const float*)d_in[2];
    const float* wq_im = (const float*)d_in[3];
    const float* wk_re = (const float*)d_in[4];
    const float* wk_im = (const float*)d_in[5];
    const float* wv_re = (const float*)d_in[6];
    const float* wv_im = (const float*)d_in[7];
    const float* wo_re = (const float*)d_in[8];
    const float* wo_im = (const float*)d_in[9];
    float* out = (float*)d_out;
    char*  base = (char*)d_ws;

    const size_t MB4  = (size_t)2048 * 2048;
    const size_t QKVP = (size_t)3072 * 2048;
    const size_t KVE  = (size_t)B_ * KV_ * S_ * 128;

    float*   mags   = (float*)(base);
    float*   invs1  = (float*)(base + 1024);
    float*   invs2  = (float*)(base + 9216);
    int8_t*  xr_q   = (int8_t*)(base + 32768);
    int8_t*  xi_q   = xr_q + MB4;
    int8_t*  qkv_sr = xi_q + MB4;
    int8_t*  qkv_si = qkv_sr + QKVP;
    int8_t*  qkv_ns = qkv_si + QKVP;
    int8_t*  wo_sr  = qkv_ns + QKVP;
    int8_t*  wo_si  = wo_sr + MB4;
    int8_t*  wo_ns  = wo_si + MB4;
    float*   q_re   = (float*)(wo_ns + MB4);
    float*   q_im   = q_re + MB4;
    uint16_t* kb_re = (uint16_t*)(q_im + MB4);
    uint16_t* kb_im = kb_re + KVE;
    uint16_t* vb_re = kb_im + KVE;
    uint16_t* vb_im = vb_re + KVE;
    uint16_t* vt_re = (uint16_t*)xr_q;
    uint16_t* vt_im = (uint16_t*)xi_q;
    uint16_t* qb_re = (uint16_t*)qkv_sr;
    uint16_t* qb_im = (uint16_t*)(qkv_sr + 8388608);

    hipMemsetAsync(mags, 0, 16, stream);

    decode_kernel<<<dim3(32, 32), 256, 0, stream>>>(wq_re, wq_im, 2048, qkv_sr, qkv_si, qkv_ns, 0,    mags + 0);
    decode_kernel<<<dim3(8, 32),  256, 0, stream>>>(wk_re, wk_im, 512,  qkv_sr, qkv_si, qkv_ns, 2048, mags + 1);
    decode_kernel<<<dim3(8, 32),  256, 0, stream>>>(wv_re, wv_im, 512,  qkv_sr, qkv_si, qkv_ns, 2560, mags + 2);
    decode_kernel<<<dim3(32, 32), 256, 0, stream>>>(wo_re, wo_im, 2048, wo_sr, wo_si, wo_ns, 0,       mags + 3);

    act_quant_i8_kernel<<<NTOK, 256, 0, stream>>>(hr, hi, xr_q, xi_q, invs1);

    gemm_i8_kernel<0><<<dim3(24, 16), 256, 0, stream>>>(
        xr_q, xi_q, qkv_sr, qkv_si, qkv_ns, 0, invs1, mags,
        1.0f / (float)((size_t)D_ * QD), 1.0f / (float)((size_t)D_ * KD), 1.0f / (float)((size_t)D_ * KD),
        q_re, q_im, kb_re, kb_im, vb_re, vb_im);

    rope_q_kernel<<<NTOK * H_ * 16 / 256, 256, 0, stream>>>(q_re, q_im, qb_re, qb_im);
    rope_k_kernel<<<NTOK * KV_ * 16 / 256, 256, 0, stream>>>(kb_re);
    vtrans_kernel<<<dim3(S_ / 32, 128 / 32, B_ * KV_ * 2), 256, 0, stream>>>(vb_re, vb_im, vt_re, vt_im);

    attn_mfma_kernel<<<dim3(S_ / 64, H_, B_), 256, 0, stream>>>(
        qb_re, qb_im, kb_re, kb_im, vt_re, vt_im, q_re, q_im);

    act_quant_i8_kernel<<<NTOK, 256, 0, stream>>>(q_re, q_im, xr_q, xi_q, invs2);

    gemm_i8_kernel<1><<<dim3(16, 16), 256, 0, stream>>>(
        xr_q, xi_q, wo_sr, wo_si, wo_ns, 2048, invs2, mags + 3,
        1.0f / (float)((size_t)QD * D_), 0.f, 0.f,
        out, out + MB4, nullptr, nullptr, nullptr, nullptr);
}